// Round 10
// baseline (515.429 us; speedup 1.0000x reference)
//
#include <hip/hip_runtime.h>

#define N_NODES 100000
#define N_HYPER 20000
#define N_EDGES 1600000
#define LDW 136   // LDS row stride in bf16 elems: 272 B = odd*16B (16B-aligned, bank-decorrelated)
#define LDY 72    // row stride for 64-col tiles: 144 B, same bank-rotation property

#define NB_HE 79      // ceil(20000/256) hyperedge buckets (id >> 8)
#define NB_ND 391     // ceil(100000/256) node buckets (id >> 8)
#define CHUNK 6250    // edges per binning block: 256 * 6250 = 1.6M exactly

typedef unsigned short u16;
typedef unsigned int u32;
typedef short bf16x8 __attribute__((ext_vector_type(8)));
typedef float f32x4 __attribute__((ext_vector_type(4)));

typedef __attribute__((address_space(3))) unsigned int lds_u32;
typedef __attribute__((address_space(1))) unsigned int gbl_u32;

__device__ __forceinline__ f32x4 mfma16(bf16x8 a, bf16x8 b, f32x4 c) {
    return __builtin_amdgcn_mfma_f32_16x16x32_bf16(a, b, c, 0, 0, 0);
}
__device__ __forceinline__ u16 f2bf(float f) {
    unsigned u = __float_as_uint(f);
    unsigned r = u + 0x7FFFu + ((u >> 16) & 1u);   // RN-even
    return (u16)(r >> 16);
}
__device__ __forceinline__ void bfu(unsigned v, float& f0, float& f1) {
    f0 = __uint_as_float(v << 16);
    f1 = __uint_as_float(v & 0xFFFF0000u);
}
// async DMA global->LDS, 16B per lane; lds dest = wave-uniform base + lane*16
__device__ __forceinline__ void dma16(const u16* g, u16* l) {
    __builtin_amdgcn_global_load_lds((const gbl_u32*)(const void*)g,
                                     (lds_u32*)(void*)l, 16, 0, 0);
}

// ------- weight prep: W1 plain; W2/W3/W4 chunked+XOR-swizzled for DMA -------
// W2s: [128 rows n][128 k], granule g=k>>3 stored at g^(n&15).
// W3s: 8 chunks of [64 rows n][128 k] bf16, 16KB each; g^(nn&15).
// W4s: 8 chunks of [128 rows n4][64 kk]; granule g=kk>>3 stored at g^(n4&7).
__global__ __launch_bounds__(256) void k_prep(const float* __restrict__ W1, const float* __restrict__ W2,
                                              const float* __restrict__ W3, const float* __restrict__ W4,
                                              u16* __restrict__ W1t, u16* __restrict__ W2t,
                                              u16* __restrict__ W3t, u16* __restrict__ W4t,
                                              const float* __restrict__ h, u16* __restrict__ h_bf) {
    int i = blockIdx.x * 256 + threadIdx.x;
    if (i < 16384) {
        int k = i & 127, n = i >> 7;
        W1t[n * 128 + k] = f2bf(W1[k * 128 + n]);
        int g2 = (k >> 3) ^ (n & 15);
        W2t[n * 128 + g2 * 8 + (k & 7)] = f2bf(W2[k * 128 + n]);
    }
    if (i < 65536) {
        int k = i & 127, n = i >> 7;          // n < 512 hidden
        int hc = n >> 6, nn = n & 63;
        int g3 = (k >> 3) ^ (nn & 15);
        W3t[hc * 8192 + nn * 128 + g3 * 8 + (k & 7)] = f2bf(W3[k * 512 + n]);
        int k4 = i & 511, n4 = i >> 9;        // n4 < 128 out-col, k4 < 512 hidden
        int hc4 = k4 >> 6, kk = k4 & 63;
        int g4 = (kk >> 3) ^ (n4 & 7);
        W4t[hc4 * 8192 + n4 * 64 + g4 * 8 + (kk & 7)] = f2bf(W4[k4 * 128 + n4]);
    }
    if (i < 3276800) {                        // 12.8M elems / 4
        float4 v = ((const float4*)h)[i];
        uint2 st;
        st.x = (u32)f2bf(v.x) | ((u32)f2bf(v.y) << 16);
        st.y = (u32)f2bf(v.z) | ((u32)f2bf(v.w) << 16);
        ((uint2*)h_bf)[i] = st;
    }
}

// ------- binning phase 1: LDS-privatized bucket histogram -------------------
__global__ __launch_bounds__(256) void k_bin_hist(const int* __restrict__ src, const int* __restrict__ dst,
                                                  int* __restrict__ bkt_he, int* __restrict__ bkt_nd) {
    __shared__ int hh[NB_HE], hn[NB_ND];
    int t = threadIdx.x;
    for (int i = t; i < NB_HE; i += 256) hh[i] = 0;
    for (int i = t; i < NB_ND; i += 256) hn[i] = 0;
    __syncthreads();
    int e0 = blockIdx.x * CHUNK;
    for (int e = e0 + t; e < e0 + CHUNK; e += 256) {
        atomicAdd(&hn[src[e] >> 8], 1);
        atomicAdd(&hh[dst[e] >> 8], 1);
    }
    __syncthreads();
    for (int i = t; i < NB_HE; i += 256) if (hh[i]) atomicAdd(&bkt_he[i], hh[i]);
    for (int i = t; i < NB_ND; i += 256) if (hn[i]) atomicAdd(&bkt_nd[i], hn[i]);
}

// ------- binning phase 2: parallel exclusive scan of bucket counts ----------
__global__ __launch_bounds__(512) void k_bin_scan(int* __restrict__ bkt_he, int* __restrict__ bkt_nd,
                                                  int* __restrict__ start_he, int* __restrict__ start_nd,
                                                  int* __restrict__ ptr_node, int* __restrict__ ptr_he) {
    __shared__ int sc[512];
    int t = threadIdx.x;
    int vhe = (t < NB_HE) ? bkt_he[t] : 0;
    sc[t] = vhe; __syncthreads();
    for (int off = 1; off < 512; off <<= 1) {
        int v = (t >= off) ? sc[t - off] : 0; __syncthreads();
        sc[t] += v; __syncthreads();
    }
    if (t < NB_HE) { int ex = sc[t] - vhe; start_he[t] = ex; bkt_he[t] = ex; }
    if (t == NB_HE - 1) start_he[NB_HE] = sc[t];
    __syncthreads();
    int vnd = (t < NB_ND) ? bkt_nd[t] : 0;
    sc[t] = vnd; __syncthreads();
    for (int off = 1; off < 512; off <<= 1) {
        int v = (t >= off) ? sc[t - off] : 0; __syncthreads();
        sc[t] += v; __syncthreads();
    }
    if (t < NB_ND) { int ex = sc[t] - vnd; start_nd[t] = ex; bkt_nd[t] = ex; }
    if (t == NB_ND - 1) start_nd[NB_ND] = sc[t];
    if (t == 0) { ptr_node[N_NODES] = N_EDGES; ptr_he[N_HYPER] = N_EDGES; }
}

// ------- binning phase 3: scatter packed (local_id<<24 | payload) -----------
__global__ __launch_bounds__(256) void k_bin_fill(const int* __restrict__ src, const int* __restrict__ dst,
                                                  int* __restrict__ bkt_he, int* __restrict__ bkt_nd,
                                                  u32* __restrict__ bin_he, u32* __restrict__ bin_nd) {
    __shared__ int hh[NB_HE], hn[NB_ND], bh[NB_HE], bn[NB_ND];
    int t = threadIdx.x;
    for (int i = t; i < NB_HE; i += 256) hh[i] = 0;
    for (int i = t; i < NB_ND; i += 256) hn[i] = 0;
    __syncthreads();
    int e0 = blockIdx.x * CHUNK;
    for (int e = e0 + t; e < e0 + CHUNK; e += 256) {
        atomicAdd(&hn[src[e] >> 8], 1);
        atomicAdd(&hh[dst[e] >> 8], 1);
    }
    __syncthreads();
    for (int i = t; i < NB_HE; i += 256) { int c = hh[i]; bh[i] = c ? atomicAdd(&bkt_he[i], c) : 0; }
    for (int i = t; i < NB_ND; i += 256) { int c = hn[i]; bn[i] = c ? atomicAdd(&bkt_nd[i], c) : 0; }
    __syncthreads();
    for (int i = t; i < NB_HE; i += 256) hh[i] = 0;
    for (int i = t; i < NB_ND; i += 256) hn[i] = 0;
    __syncthreads();
    for (int e = e0 + t; e < e0 + CHUNK; e += 256) {
        int s = src[e], d = dst[e];
        int bd = d >> 8, bs_ = s >> 8;
        int ph = bh[bd] + atomicAdd(&hh[bd], 1);
        bin_he[ph] = ((u32)(d & 255) << 24) | (u32)s;     // s < 2^17
        int pn = bn[bs_] + atomicAdd(&hn[bs_], 1);
        bin_nd[pn] = ((u32)(s & 255) << 24) | (u32)d;     // d < 2^15
    }
}

// ------- degrees from binned data -------------------------------------------
__global__ __launch_bounds__(256) void k_deg(const u32* __restrict__ bin_he, const u32* __restrict__ bin_nd,
                                             const int* __restrict__ start_he, const int* __restrict__ start_nd,
                                             int* __restrict__ deg_nd, int* __restrict__ deg_he) {
    __shared__ int cnt[256];
    int t = threadIdx.x, b = blockIdx.x;
    cnt[t] = 0; __syncthreads();
    if (b < NB_HE) {
        int lo = start_he[b], hi = start_he[b + 1];
        for (int j = lo + t; j < hi; j += 256) atomicAdd(&cnt[bin_he[j] >> 24], 1);
        __syncthreads();
        int id = b * 256 + t;
        if (id < N_HYPER) deg_he[id] = cnt[t];
    } else {
        int bb = b - NB_HE;
        int lo = start_nd[bb], hi = start_nd[bb + 1];
        for (int j = lo + t; j < hi; j += 256) atomicAdd(&cnt[bin_nd[j] >> 24], 1);
        __syncthreads();
        int id = bb * 256 + t;
        if (id < N_NODES) deg_nd[id] = cnt[t];
    }
}

// ------- multi-block scan, phase A: per-block sums --------------------------
__global__ __launch_bounds__(256) void k_scanA(const int* __restrict__ a_node,
                                               const int* __restrict__ a_he,
                                               int* __restrict__ bs) {
    __shared__ int red[256];
    int b = blockIdx.x;
    const int* a; int base, n;
    if (b < 25) { a = a_node; base = b * 4096; n = N_NODES; }
    else        { a = a_he;   base = (b - 25) * 4096; n = N_HYPER; }
    int t = threadIdx.x;
    int lo = base + t * 16;
    int s = 0;
#pragma unroll
    for (int i = 0; i < 16; ++i) {
        int idx = lo + i;
        if (idx < n) s += a[idx];
    }
    red[t] = s;
    __syncthreads();
    for (int off = 128; off > 0; off >>= 1) {
        if (t < off) red[t] += red[t + off];
        __syncthreads();
    }
    if (t == 0) bs[b] = red[0];
}

// ------- phase B: exclusive scan of the 25+5 block sums ---------------------
__global__ void k_scanB(int* __restrict__ bs) {
    int t = threadIdx.x;
    if (t == 0) {
        int run = 0;
        for (int i = 0; i < 25; ++i) { int v = bs[i]; bs[i] = run; run += v; }
    } else if (t == 1) {
        int run = 0;
        for (int i = 25; i < 30; ++i) { int v = bs[i]; bs[i] = run; run += v; }
    }
}

// ------- phase C: block-local scan + apply base; emit CSR starts + rsqrt ----
__global__ __launch_bounds__(256) void k_scanC(int* __restrict__ a_node, int* __restrict__ a_he,
                                               float* __restrict__ iq_node, float* __restrict__ iq_he,
                                               const int* __restrict__ bs) {
    __shared__ int pre[256];
    int b = blockIdx.x;
    int* a; float* iq; int base, n;
    if (b < 25) { a = a_node; iq = iq_node; base = b * 4096; n = N_NODES; }
    else        { a = a_he;   iq = iq_he;   base = (b - 25) * 4096; n = N_HYPER; }
    int t = threadIdx.x;
    int lo = base + t * 16;
    int loc = 0;
#pragma unroll
    for (int i = 0; i < 16; ++i) { int idx = lo + i; if (idx < n) loc += a[idx]; }
    pre[t] = loc;
    __syncthreads();
    for (int off = 1; off < 256; off <<= 1) {
        int v = (t >= off) ? pre[t - off] : 0;
        __syncthreads();
        pre[t] += v;
        __syncthreads();
    }
    int running = bs[b] + pre[t] - loc;   // global exclusive prefix for this thread
#pragma unroll
    for (int i = 0; i < 16; ++i) {
        int idx = lo + i;
        if (idx < n) {
            int d = a[idx];
            iq[idx] = rsqrtf((float)(d < 1 ? 1 : d));
            a[idx] = running;             // CSR segment START (sentinel set in k_bin_scan)
            running += d;
        }
    }
}

// ------- final CSR fill from bins: bucket-per-block, LDS base+rank ----------
__global__ __launch_bounds__(256) void k_fill2(const u32* __restrict__ bin_he, const u32* __restrict__ bin_nd,
                                               const int* __restrict__ start_he, const int* __restrict__ start_nd,
                                               const int* __restrict__ ptr_he, const int* __restrict__ ptr_node,
                                               int* __restrict__ adj_he, int* __restrict__ adj_node) {
    __shared__ int base[256], rk[256];
    int t = threadIdx.x, b = blockIdx.x;
    rk[t] = 0;
    if (b < NB_HE) {
        int id = b * 256 + t;
        base[t] = (id < N_HYPER) ? ptr_he[id] : 0;
        __syncthreads();
        int lo = start_he[b], hi = start_he[b + 1];
        for (int j = lo + t; j < hi; j += 256) {
            u32 v = bin_he[j];
            int lid = v >> 24;
            int pos = base[lid] + atomicAdd(&rk[lid], 1);
            adj_he[pos] = (int)(v & 0xFFFFFFu);
        }
    } else {
        int bb = b - NB_HE;
        int id = bb * 256 + t;
        base[t] = (id < N_NODES) ? ptr_node[id] : 0;
        __syncthreads();
        int lo = start_nd[bb], hi = start_nd[bb + 1];
        for (int j = lo + t; j < hi; j += 256) {
            u32 v = bin_nd[j];
            int lid = v >> 24;
            int pos = base[lid] + atomicAdd(&rk[lid], 1);
            adj_node[pos] = (int)(v & 0xFFFFFFu);
        }
    }
}

// ------- gather 1: acc1[d] = sum_{s in adj_he[d]} h_bf[s] * cn[s] -----------
// nt adj loads (zero reuse) + nt acc1 stores: protect h_bf L2 residency.
__global__ __launch_bounds__(256) void k_gather1(const u16* __restrict__ h_bf,
                                                 const int* __restrict__ adj,
                                                 const int* __restrict__ ptr,
                                                 const float* __restrict__ cn,
                                                 float* __restrict__ acc1) {
    int row = blockIdx.x * 4 + (threadIdx.x >> 6);
    int lane = threadIdx.x & 63;
    int p = lane >> 5, c = lane & 31;
    int start = ptr[row];
    int end = ptr[row + 1];
    const uint2* hp = (const uint2*)h_bf;
    float A0[4] = {0, 0, 0, 0}, A1[4] = {0, 0, 0, 0};
    float f0, f1, f2, f3;
    int j = start;
    for (; j + 3 < end; j += 4) {
        int sA = __builtin_nontemporal_load(adj + j + p);
        int sB = __builtin_nontemporal_load(adj + j + 2 + p);
        float wA = cn[sA], wB = cn[sB];
        uint2 vA = hp[sA * 32 + c];
        uint2 vB = hp[sB * 32 + c];
        bfu(vA.x, f0, f1); bfu(vA.y, f2, f3);
        A0[0] += f0 * wA; A0[1] += f1 * wA; A0[2] += f2 * wA; A0[3] += f3 * wA;
        bfu(vB.x, f0, f1); bfu(vB.y, f2, f3);
        A1[0] += f0 * wB; A1[1] += f1 * wB; A1[2] += f2 * wB; A1[3] += f3 * wB;
    }
    for (; j + 1 < end; j += 2) {
        int sA = __builtin_nontemporal_load(adj + j + p);
        float wA = cn[sA];
        uint2 vA = hp[sA * 32 + c];
        bfu(vA.x, f0, f1); bfu(vA.y, f2, f3);
        A0[0] += f0 * wA; A0[1] += f1 * wA; A0[2] += f2 * wA; A0[3] += f3 * wA;
    }
    if (j < end && p == 0) {
        int sA = __builtin_nontemporal_load(adj + j);
        float wA = cn[sA];
        uint2 vA = hp[sA * 32 + c];
        bfu(vA.x, f0, f1); bfu(vA.y, f2, f3);
        A0[0] += f0 * wA; A0[1] += f1 * wA; A0[2] += f2 * wA; A0[3] += f3 * wA;
    }
    float r0 = A0[0] + A1[0], r1 = A0[1] + A1[1], r2 = A0[2] + A1[2], r3 = A0[3] + A1[3];
    r0 += __shfl_xor(r0, 32, 64);
    r1 += __shfl_xor(r1, 32, 64);
    r2 += __shfl_xor(r2, 32, 64);
    r3 += __shfl_xor(r3, 32, 64);
    if (p == 0) {
        f32x4 o = {r0, r1, r2, r3};
        __builtin_nontemporal_store(o, (f32x4*)acc1 + row * 32 + c);
    }
}

// ------- gather 2: acc2[s] = sum_{d in adj_node[s]} hh2b[d] -----------------
// nt acc2 stores: 51MB write-allocate would thrash the 5.1MB hh2b table.
__global__ __launch_bounds__(256) void k_gather2(const u16* __restrict__ hh2b,
                                                 const int* __restrict__ adj,
                                                 const int* __restrict__ ptr,
                                                 float* __restrict__ acc2) {
    int row = blockIdx.x * 4 + (threadIdx.x >> 6);
    int lane = threadIdx.x & 63;
    int p = lane >> 5, c = lane & 31;
    int start = ptr[row];
    int end = ptr[row + 1];
    const uint2* hp = (const uint2*)hh2b;
    float A0[4] = {0, 0, 0, 0}, A1[4] = {0, 0, 0, 0};
    float f0, f1, f2, f3;
    int j = start;
    for (; j + 3 < end; j += 4) {
        int dA = __builtin_nontemporal_load(adj + j + p);
        int dB = __builtin_nontemporal_load(adj + j + 2 + p);
        uint2 vA = hp[dA * 32 + c];
        uint2 vB = hp[dB * 32 + c];
        bfu(vA.x, f0, f1); bfu(vA.y, f2, f3);
        A0[0] += f0; A0[1] += f1; A0[2] += f2; A0[3] += f3;
        bfu(vB.x, f0, f1); bfu(vB.y, f2, f3);
        A1[0] += f0; A1[1] += f1; A1[2] += f2; A1[3] += f3;
    }
    for (; j + 1 < end; j += 2) {
        int dA = __builtin_nontemporal_load(adj + j + p);
        uint2 vA = hp[dA * 32 + c];
        bfu(vA.x, f0, f1); bfu(vA.y, f2, f3);
        A0[0] += f0; A0[1] += f1; A0[2] += f2; A0[3] += f3;
    }
    if (j < end && p == 0) {
        int dA = __builtin_nontemporal_load(adj + j);
        uint2 vA = hp[dA * 32 + c];
        bfu(vA.x, f0, f1); bfu(vA.y, f2, f3);
        A0[0] += f0; A0[1] += f1; A0[2] += f2; A0[3] += f3;
    }
    float r0 = A0[0] + A1[0], r1 = A0[1] + A1[1], r2 = A0[2] + A1[2], r3 = A0[3] + A1[3];
    r0 += __shfl_xor(r0, 32, 64);
    r1 += __shfl_xor(r1, 32, 64);
    r2 += __shfl_xor(r2, 32, 64);
    r3 += __shfl_xor(r3, 32, 64);
    if (p == 0) {
        f32x4 o = {r0, r1, r2, r3};
        __builtin_nontemporal_store(o, (f32x4*)acc2 + row * 32 + c);
    }
}

// ------- GEMM1 (MFMA): hh2b = bf16(((acc1*ch) @ W1 + b1) * ch) --------------
__global__ __launch_bounds__(256) void k_gemm1(const float* __restrict__ a, const float* __restrict__ ch,
                                               const u16* __restrict__ W1t,
                                               const float* __restrict__ b1,
                                               u16* __restrict__ hh2b) {
    __shared__ u16 sA[64 * LDW];
    __shared__ u16 sW[128 * LDW];
    int tid = threadIdx.x;
    int r0 = blockIdx.x * 64;
    for (int i = tid; i < 64 * 32; i += 256) {
        int r = i >> 5, c4 = i & 31;
        int row = r0 + r; if (row > N_HYPER - 1) row = N_HYPER - 1;
        float4 v = *(const float4*)(a + row * 128 + c4 * 4);
        float cw = ch[row];
        u16* p = &sA[r * LDW + c4 * 4];
        p[0] = f2bf(v.x * cw); p[1] = f2bf(v.y * cw);
        p[2] = f2bf(v.z * cw); p[3] = f2bf(v.w * cw);
    }
    for (int i = tid; i < 128 * 16; i += 256) {
        int n = i >> 4, c = i & 15;
        *(uint4*)&sW[n * LDW + c * 8] = *(const uint4*)(W1t + n * 128 + c * 8);
    }
    __syncthreads();
    int w = tid >> 6, l15 = tid & 15, quad = (tid & 63) >> 4;
    f32x4 zero = {0.f, 0.f, 0.f, 0.f};
    f32x4 acc[8];
#pragma unroll
    for (int nt = 0; nt < 8; ++nt) acc[nt] = zero;
    int arow = w * 16 + l15;
#pragma unroll
    for (int kt = 0; kt < 4; ++kt) {
        bf16x8 af = *(bf16x8*)&sA[arow * LDW + kt * 32 + quad * 8];
#pragma unroll
        for (int nt = 0; nt < 8; ++nt) {
            bf16x8 bfv = *(bf16x8*)&sW[(nt * 16 + l15) * LDW + kt * 32 + quad * 8];
            acc[nt] = mfma16(af, bfv, acc[nt]);
        }
    }
#pragma unroll
    for (int r = 0; r < 4; ++r) {
        int row = r0 + w * 16 + quad * 4 + r;
        if (row < N_HYPER) {
            float cw = ch[row];
#pragma unroll
            for (int nt = 0; nt < 8; ++nt) {
                int n = nt * 16 + l15;
                hh2b[row * 128 + n] = f2bf((acc[nt][r] + b1[n]) * cw);
            }
        }
    }
}

// --- GEMM2 + residual + LN1: DMA weight staging (round-9 recipe) ------------
// W2 pre-swizzled in global (k_prep); 32KB DMA'd linearly into sW BEFORE the
// sA staging so the f2bf VALU work covers the DMA flight; __syncthreads then
// waits on a transfer that has had the whole staging phase to land.
__global__ __launch_bounds__(256) void k_gemm2_ln(float* a, const float* __restrict__ cn,
                                                  const u16* __restrict__ W2s,
                                                  const float* __restrict__ b2,
                                                  const float* __restrict__ h,
                                                  const float* __restrict__ gamma1,
                                                  const float* __restrict__ beta1) {
    __shared__ __align__(16) u16 sA[64 * LDW];
    __shared__ __align__(16) u16 sW[16384];      // 32 KB linear, swizzled layout
    int tid = threadIdx.x;
    int w = tid >> 6, lane = tid & 63;
    int r0 = blockIdx.x * 64;
    // fire DMA first: wave w covers bytes w*8192 .. w*8192+8191
#pragma unroll
    for (int j = 0; j < 8; ++j)
        dma16((const u16*)((const char*)W2s + w * 8192 + j * 1024 + lane * 16),
              (u16*)((char*)sW + w * 8192 + j * 1024));
    for (int i = tid; i < 64 * 32; i += 256) {
        int r = i >> 5, c4 = i & 31;
        int row = r0 + r; if (row > N_NODES - 1) row = N_NODES - 1;
        float4 v = *(const float4*)(a + row * 128 + c4 * 4);
        float cw = cn[row];
        u16* p = &sA[r * LDW + c4 * 4];
        p[0] = f2bf(v.x * cw); p[1] = f2bf(v.y * cw);
        p[2] = f2bf(v.z * cw); p[3] = f2bf(v.w * cw);
    }
    __syncthreads();
    int l15 = tid & 15, quad = (tid & 63) >> 4;
    f32x4 zero = {0.f, 0.f, 0.f, 0.f};
    f32x4 acc[8];
#pragma unroll
    for (int nt = 0; nt < 8; ++nt) acc[nt] = zero;
    int arow = w * 16 + l15;
#pragma unroll
    for (int kt = 0; kt < 4; ++kt) {
        bf16x8 af = *(bf16x8*)&sA[arow * LDW + kt * 32 + quad * 8];
#pragma unroll
        for (int nt = 0; nt < 8; ++nt) {
            int r = nt * 16 + l15;
            bf16x8 bfv = *(bf16x8*)&sW[r * 128 + ((((kt << 2) + quad) ^ l15) << 3)];
            acc[nt] = mfma16(af, bfv, acc[nt]);
        }
    }
    float s1[4] = {0, 0, 0, 0}, s2[4] = {0, 0, 0, 0};
#pragma unroll
    for (int r = 0; r < 4; ++r) {
        int row = r0 + w * 16 + quad * 4 + r;
        int rc = row > N_NODES - 1 ? N_NODES - 1 : row;
#pragma unroll
        for (int nt = 0; nt < 8; ++nt) {
            int n = nt * 16 + l15;
            float t = acc[nt][r] + b2[n] + h[rc * 128 + n];
            acc[nt][r] = t;
            s1[r] += t; s2[r] += t * t;
        }
    }
#pragma unroll
    for (int off = 1; off < 16; off <<= 1) {
#pragma unroll
        for (int r = 0; r < 4; ++r) {
            s1[r] += __shfl_xor(s1[r], off, 64);
            s2[r] += __shfl_xor(s2[r], off, 64);
        }
    }
#pragma unroll
    for (int r = 0; r < 4; ++r) {
        int row = r0 + w * 16 + quad * 4 + r;
        if (row < N_NODES) {
            float mu = s1[r] * (1.f / 128.f);
            float var = s2[r] * (1.f / 128.f) - mu * mu;
            float rs = rsqrtf(var + 1e-5f);
#pragma unroll
            for (int nt = 0; nt < 8; ++nt) {
                int n = nt * 16 + l15;
                a[row * 128 + n] = (acc[nt][r] - mu) * rs * gamma1[n] + beta1[n];
            }
        }
    }
}

// ------- FFN + residual + LN2: async global_load_lds weight pipeline --------
// (unchanged from round 9: 91.5 us, no spill)
__global__ __launch_bounds__(256) void k_ffn_ln(const float* __restrict__ h1,
                                                const u16* __restrict__ W3s,
                                                const float* __restrict__ b3,
                                                const u16* __restrict__ W4s,
                                                const float* __restrict__ b4,
                                                const float* __restrict__ gamma2,
                                                const float* __restrict__ beta2,
                                                float* __restrict__ out) {
    __shared__ __align__(16) u16 sA[64 * LDW];   // 17.4 KB
    __shared__ __align__(16) u16 sY[64 * LDY];   //  9.2 KB (wave-private rows)
    __shared__ __align__(16) u16 sW3[8192];      // 16 KB linear W3 chunk
    __shared__ __align__(16) u16 sW4[8192];      // 16 KB linear W4 chunk
    int tid = threadIdx.x;
    int w = tid >> 6, lane = tid & 63;
    int l15 = tid & 15, quad = (tid & 63) >> 4;
    int r0 = blockIdx.x * 64;
    int dmaoff = w * 4096 + lane * 16;           // bytes; +j*1024 per call

    // prologue: fire DMA for W3[0] and W4[0], then stage sA
#pragma unroll
    for (int j = 0; j < 4; ++j)
        dma16((const u16*)((const char*)W3s + dmaoff + j * 1024),
              (u16*)((char*)sW3 + w * 4096 + j * 1024));
#pragma unroll
    for (int j = 0; j < 4; ++j)
        dma16((const u16*)((const char*)W4s + dmaoff + j * 1024),
              (u16*)((char*)sW4 + w * 4096 + j * 1024));
    for (int i = tid; i < 64 * 32; i += 256) {
        int r = i >> 5, c4 = i & 31;
        int row = r0 + r; if (row > N_NODES - 1) row = N_NODES - 1;
        float4 v = *(const float4*)(h1 + row * 128 + c4 * 4);
        uint2 st;
        st.x = (u32)f2bf(v.x) | ((u32)f2bf(v.y) << 16);
        st.y = (u32)f2bf(v.z) | ((u32)f2bf(v.w) << 16);
        *(uint2*)&sA[r * LDW + c4 * 4] = st;
    }
    asm volatile("s_waitcnt vmcnt(4) lgkmcnt(0)" ::: "memory");  // W3[0]+sA ready; W4[0] flying
    __builtin_amdgcn_s_barrier();
    __builtin_amdgcn_sched_barrier(0);

    int arow = w * 16 + l15;
    f32x4 zero = {0.f, 0.f, 0.f, 0.f};
    f32x4 acc[8];
#pragma unroll
    for (int nt = 0; nt < 8; ++nt) acc[nt] = zero;

    for (int hc = 0; hc < 8; ++hc) {
        // gemmA: Y[16x64/wave] = sA @ W3chunk (swizzled read)
        f32x4 y[4];
#pragma unroll
        for (int nt = 0; nt < 4; ++nt) y[nt] = zero;
#pragma unroll
        for (int kt = 0; kt < 4; ++kt) {
            bf16x8 af = *(bf16x8*)&sA[arow * LDW + kt * 32 + quad * 8];
#pragma unroll
            for (int nt = 0; nt < 4; ++nt) {
                int r = nt * 16 + l15;
                bf16x8 bv = *(bf16x8*)&sW3[r * 128 + ((((kt << 2) + quad) ^ l15) << 3)];
                y[nt] = mfma16(af, bv, y[nt]);
            }
        }
        // bias + relu -> sY (wave-private rows)
#pragma unroll
        for (int r = 0; r < 4; ++r) {
            int yrow = w * 16 + quad * 4 + r;
#pragma unroll
            for (int nt = 0; nt < 4; ++nt) {
                int n = nt * 16 + l15;
                float vv = y[nt][r] + b3[hc * 64 + n];
                sY[yrow * LDY + n] = f2bf(vv > 0.f ? vv : 0.f);
            }
        }
        __builtin_amdgcn_s_barrier();            // all done reading sW3[hc]
        __builtin_amdgcn_sched_barrier(0);
        {   // DMA W3[next] (dummy wrap at hc==7 keeps vmcnt counting uniform)
            const char* g3 = (const char*)W3s + ((hc + 1) & 7) * 16384;
#pragma unroll
            for (int j = 0; j < 4; ++j)
                dma16((const u16*)(g3 + dmaoff + j * 1024),
                      (u16*)((char*)sW3 + w * 4096 + j * 1024));
        }
        asm volatile("s_waitcnt vmcnt(4)" ::: "memory");  // own W4[hc] arrived
        __builtin_amdgcn_s_barrier();            // everyone's W4[hc] visible
        __builtin_amdgcn_sched_barrier(0);
        // gemmB: acc += Y @ W4chunk (K=64, swizzled read)
#pragma unroll
        for (int kt = 0; kt < 2; ++kt) {
            bf16x8 ay = *(bf16x8*)&sY[arow * LDY + kt * 32 + quad * 8];
#pragma unroll
            for (int nt = 0; nt < 8; ++nt) {
                int rr = nt * 16 + l15;
                bf16x8 bv = *(bf16x8*)&sW4[rr * 64 + ((((kt << 2) + quad) ^ (l15 & 7)) << 3)];
                acc[nt] = mfma16(ay, bv, acc[nt]);
            }
        }
        if (hc == 7) break;
        __builtin_amdgcn_s_barrier();            // all done reading sW4[hc]
        __builtin_amdgcn_sched_barrier(0);
        {   // DMA W4[hc+1]
            const char* g4 = (const char*)W4s + (hc + 1) * 16384;
#pragma unroll
            for (int j = 0; j < 4; ++j)
                dma16((const u16*)(g4 + dmaoff + j * 1024),
                      (u16*)((char*)sW4 + w * 4096 + j * 1024));
        }
        asm volatile("s_waitcnt vmcnt(4)" ::: "memory");  // own W3[hc+1] arrived
        __builtin_amdgcn_s_barrier();            // everyone's W3[hc+1] visible
        __builtin_amdgcn_sched_barrier(0);
    }
    // epilogue: residual + LN2 (round-4 proven)
    float s1[4] = {0, 0, 0, 0}, s2[4] = {0, 0, 0, 0};
#pragma unroll
    for (int r = 0; r < 4; ++r) {
        int row = r0 + w * 16 + quad * 4 + r;
        int rc = row > N_NODES - 1 ? N_NODES - 1 : row;
#pragma unroll
        for (int nt = 0; nt < 8; ++nt) {
            int n = nt * 16 + l15;
            float t = acc[nt][r] + b4[n] + h1[rc * 128 + n];
            acc[nt][r] = t;
            s1[r] += t; s2[r] += t * t;
        }
    }
#pragma unroll
    for (int off = 1; off < 16; off <<= 1) {
#pragma unroll
        for (int r = 0; r < 4; ++r) {
            s1[r] += __shfl_xor(s1[r], off, 64);
            s2[r] += __shfl_xor(s2[r], off, 64);
        }
    }
#pragma unroll
    for (int r = 0; r < 4; ++r) {
        int row = r0 + w * 16 + quad * 4 + r;
        if (row < N_NODES) {
            float mu = s1[r] * (1.f / 128.f);
            float var = s2[r] * (1.f / 128.f) - mu * mu;
            float rs = rsqrtf(var + 1e-5f);
#pragma unroll
            for (int nt = 0; nt < 8; ++nt) {
                int n = nt * 16 + l15;
                out[row * 128 + n] = (acc[nt][r] - mu) * rs * gamma2[n] + beta2[n];
            }
        }
    }
}

extern "C" void kernel_launch(void* const* d_in, const int* in_sizes, int n_in,
                              void* d_out, int out_size, void* d_ws, size_t ws_size,
                              hipStream_t stream) {
    const float* h      = (const float*)d_in[0];
    const int*   src    = (const int*)d_in[1];
    const int*   dst    = (const int*)d_in[2];
    const float* W1     = (const float*)d_in[3];
    const float* b1     = (const float*)d_in[4];
    const float* W2     = (const float*)d_in[5];
    const float* b2     = (const float*)d_in[6];
    const float* W3     = (const float*)d_in[7];
    const float* b3     = (const float*)d_in[8];
    const float* W4     = (const float*)d_in[9];
    const float* b4     = (const float*)d_in[10];
    const float* gamma1 = (const float*)d_in[11];
    const float* beta1  = (const float*)d_in[12];
    const float* gamma2 = (const float*)d_in[13];
    const float* beta2  = (const float*)d_in[14];
    float* out = (float*)d_out;

    // ws layout (bytes), with dead-region aliasing (same as round 4):
    char* ws = (char*)d_ws;
    int*   ptr_node = (int*)(ws + 0);
    int*   ptr_he   = (int*)(ws + 400512);
    int*   adj_he   = (int*)(ws + 481280);
    int*   adj_node = (int*)(ws + 6881280);
    float* cn       = (float*)(ws + 13281280);
    float* ch       = (float*)(ws + 13681280);
    u16*   h_bf     = (u16*)(ws + 24000000);
    u32*   bin_he   = (u32*)(ws + 49600000);
    u32*   bin_nd   = (u32*)(ws + 56000000);
    float* acc1     = (float*)(ws + 62400000);
    int*   bkt_he   = (int*)(ws + 72640000);
    int*   bkt_nd   = (int*)(ws + 72640512);
    int*   start_he = (int*)(ws + 72642560);
    int*   start_nd = (int*)(ws + 72643072);
    int*   bs       = (int*)(ws + 72644864);
    float* acc2     = (float*)(ws + 24000000);
    u16*   hh2b     = (u16*)(ws + 481280);     // alias adj_he (dead after gather1)
    u16*   W1t      = (u16*)(ws + 75200000);
    u16*   W2t      = (u16*)(ws + 75232768);
    u16*   W3t      = (u16*)(ws + 75265536);
    u16*   W4t      = (u16*)(ws + 75396608);

    hipMemsetAsync(ws + 72640000, 0, 2560, stream);   // zero bucket counters only

    k_prep<<<12800, 256, 0, stream>>>(W1, W2, W3, W4, W1t, W2t, W3t, W4t, h, h_bf);
    k_bin_hist<<<256, 256, 0, stream>>>(src, dst, bkt_he, bkt_nd);
    k_bin_scan<<<1, 512, 0, stream>>>(bkt_he, bkt_nd, start_he, start_nd, ptr_node, ptr_he);
    k_bin_fill<<<256, 256, 0, stream>>>(src, dst, bkt_he, bkt_nd, bin_he, bin_nd);
    k_deg<<<NB_HE + NB_ND, 256, 0, stream>>>(bin_he, bin_nd, start_he, start_nd, ptr_node, ptr_he);
    k_scanA<<<30, 256, 0, stream>>>(ptr_node, ptr_he, bs);
    k_scanB<<<1, 64, 0, stream>>>(bs);
    k_scanC<<<30, 256, 0, stream>>>(ptr_node, ptr_he, cn, ch, bs);
    k_fill2<<<NB_HE + NB_ND, 256, 0, stream>>>(bin_he, bin_nd, start_he, start_nd,
                                               ptr_he, ptr_node, adj_he, adj_node);
    k_gather1<<<5000, 256, 0, stream>>>(h_bf, adj_he, ptr_he, cn, acc1);
    k_gemm1<<<313, 256, 0, stream>>>(acc1, ch, W1t, b1, hh2b);
    k_gather2<<<25000, 256, 0, stream>>>(hh2b, adj_node, ptr_node, acc2);
    k_gemm2_ln<<<1563, 256, 0, stream>>>(acc2, cn, W2t, b2, h, gamma1, beta1);
    k_ffn_ln<<<1563, 256, 0, stream>>>(acc2, W3t, b3, W4t, b4, gamma2, beta2, out);
}

// Round 11
// 475.867 us; speedup vs baseline: 1.0831x; 1.0831x over previous
//
#include <hip/hip_runtime.h>

#define N_NODES 100000
#define N_HYPER 20000
#define N_EDGES 1600000
#define LDW 136   // LDS row stride in bf16 elems: 272 B = odd*16B (16B-aligned, bank-decorrelated)
#define LDY 72    // row stride for 64-col tiles: 144 B, same bank-rotation property

#define NB_HE 79      // ceil(20000/256) hyperedge buckets (id >> 8)
#define NB_ND 391     // ceil(100000/256) node buckets (id >> 8)
#define CHUNK 6250    // edges per binning block: 256 * 6250 = 1.6M exactly

typedef unsigned short u16;
typedef unsigned int u32;
typedef short bf16x8 __attribute__((ext_vector_type(8)));
typedef float f32x4 __attribute__((ext_vector_type(4)));

typedef __attribute__((address_space(3))) unsigned int lds_u32;
typedef __attribute__((address_space(1))) unsigned int gbl_u32;

__device__ __forceinline__ f32x4 mfma16(bf16x8 a, bf16x8 b, f32x4 c) {
    return __builtin_amdgcn_mfma_f32_16x16x32_bf16(a, b, c, 0, 0, 0);
}
__device__ __forceinline__ u16 f2bf(float f) {
    unsigned u = __float_as_uint(f);
    unsigned r = u + 0x7FFFu + ((u >> 16) & 1u);   // RN-even
    return (u16)(r >> 16);
}
__device__ __forceinline__ void bfu(unsigned v, float& f0, float& f1) {
    f0 = __uint_as_float(v << 16);
    f1 = __uint_as_float(v & 0xFFFF0000u);
}
// async DMA global->LDS, 16B per lane; lds dest = wave-uniform base + lane*16
__device__ __forceinline__ void dma16(const u16* g, u16* l) {
    __builtin_amdgcn_global_load_lds((const gbl_u32*)(const void*)g,
                                     (lds_u32*)(void*)l, 16, 0, 0);
}

// ------- weight prep: W1/W2 plain; W3/W4 chunked+XOR-swizzled for DMA -------
// W3s: 8 chunks of [64 rows n][128 k] bf16, 16KB each; granule g=k>>3 stored
// at g^(nn&15). W4s: 8 chunks of [128 rows n4][64 kk]; g=kk>>3 at g^(n4&7).
__global__ __launch_bounds__(256) void k_prep(const float* __restrict__ W1, const float* __restrict__ W2,
                                              const float* __restrict__ W3, const float* __restrict__ W4,
                                              u16* __restrict__ W1t, u16* __restrict__ W2t,
                                              u16* __restrict__ W3t, u16* __restrict__ W4t,
                                              const float* __restrict__ h, u16* __restrict__ h_bf) {
    int i = blockIdx.x * 256 + threadIdx.x;
    if (i < 16384) {
        int k = i & 127, n = i >> 7;
        W1t[n * 128 + k] = f2bf(W1[k * 128 + n]);
        W2t[n * 128 + k] = f2bf(W2[k * 128 + n]);
    }
    if (i < 65536) {
        int k = i & 127, n = i >> 7;          // n < 512 hidden
        int hc = n >> 6, nn = n & 63;
        int g3 = (k >> 3) ^ (nn & 15);
        W3t[hc * 8192 + nn * 128 + g3 * 8 + (k & 7)] = f2bf(W3[k * 512 + n]);
        int k4 = i & 511, n4 = i >> 9;        // n4 < 128 out-col, k4 < 512 hidden
        int hc4 = k4 >> 6, kk = k4 & 63;
        int g4 = (kk >> 3) ^ (n4 & 7);
        W4t[hc4 * 8192 + n4 * 64 + g4 * 8 + (kk & 7)] = f2bf(W4[k4 * 128 + n4]);
    }
    if (i < 3276800) {                        // 12.8M elems / 4
        float4 v = ((const float4*)h)[i];
        uint2 st;
        st.x = (u32)f2bf(v.x) | ((u32)f2bf(v.y) << 16);
        st.y = (u32)f2bf(v.z) | ((u32)f2bf(v.w) << 16);
        ((uint2*)h_bf)[i] = st;
    }
}

// ------- binning phase 1: LDS-privatized bucket histogram -------------------
__global__ __launch_bounds__(256) void k_bin_hist(const int* __restrict__ src, const int* __restrict__ dst,
                                                  int* __restrict__ bkt_he, int* __restrict__ bkt_nd) {
    __shared__ int hh[NB_HE], hn[NB_ND];
    int t = threadIdx.x;
    for (int i = t; i < NB_HE; i += 256) hh[i] = 0;
    for (int i = t; i < NB_ND; i += 256) hn[i] = 0;
    __syncthreads();
    int e0 = blockIdx.x * CHUNK;
    for (int e = e0 + t; e < e0 + CHUNK; e += 256) {
        atomicAdd(&hn[src[e] >> 8], 1);
        atomicAdd(&hh[dst[e] >> 8], 1);
    }
    __syncthreads();
    for (int i = t; i < NB_HE; i += 256) if (hh[i]) atomicAdd(&bkt_he[i], hh[i]);
    for (int i = t; i < NB_ND; i += 256) if (hn[i]) atomicAdd(&bkt_nd[i], hn[i]);
}

// ------- binning phase 2: parallel exclusive scan of bucket counts ----------
__global__ __launch_bounds__(512) void k_bin_scan(int* __restrict__ bkt_he, int* __restrict__ bkt_nd,
                                                  int* __restrict__ start_he, int* __restrict__ start_nd,
                                                  int* __restrict__ ptr_node, int* __restrict__ ptr_he) {
    __shared__ int sc[512];
    int t = threadIdx.x;
    int vhe = (t < NB_HE) ? bkt_he[t] : 0;
    sc[t] = vhe; __syncthreads();
    for (int off = 1; off < 512; off <<= 1) {
        int v = (t >= off) ? sc[t - off] : 0; __syncthreads();
        sc[t] += v; __syncthreads();
    }
    if (t < NB_HE) { int ex = sc[t] - vhe; start_he[t] = ex; bkt_he[t] = ex; }
    if (t == NB_HE - 1) start_he[NB_HE] = sc[t];
    __syncthreads();
    int vnd = (t < NB_ND) ? bkt_nd[t] : 0;
    sc[t] = vnd; __syncthreads();
    for (int off = 1; off < 512; off <<= 1) {
        int v = (t >= off) ? sc[t - off] : 0; __syncthreads();
        sc[t] += v; __syncthreads();
    }
    if (t < NB_ND) { int ex = sc[t] - vnd; start_nd[t] = ex; bkt_nd[t] = ex; }
    if (t == NB_ND - 1) start_nd[NB_ND] = sc[t];
    if (t == 0) { ptr_node[N_NODES] = N_EDGES; ptr_he[N_HYPER] = N_EDGES; }
}

// ------- binning phase 3: scatter packed (local_id<<24 | payload) -----------
__global__ __launch_bounds__(256) void k_bin_fill(const int* __restrict__ src, const int* __restrict__ dst,
                                                  int* __restrict__ bkt_he, int* __restrict__ bkt_nd,
                                                  u32* __restrict__ bin_he, u32* __restrict__ bin_nd) {
    __shared__ int hh[NB_HE], hn[NB_ND], bh[NB_HE], bn[NB_ND];
    int t = threadIdx.x;
    for (int i = t; i < NB_HE; i += 256) hh[i] = 0;
    for (int i = t; i < NB_ND; i += 256) hn[i] = 0;
    __syncthreads();
    int e0 = blockIdx.x * CHUNK;
    for (int e = e0 + t; e < e0 + CHUNK; e += 256) {
        atomicAdd(&hn[src[e] >> 8], 1);
        atomicAdd(&hh[dst[e] >> 8], 1);
    }
    __syncthreads();
    for (int i = t; i < NB_HE; i += 256) { int c = hh[i]; bh[i] = c ? atomicAdd(&bkt_he[i], c) : 0; }
    for (int i = t; i < NB_ND; i += 256) { int c = hn[i]; bn[i] = c ? atomicAdd(&bkt_nd[i], c) : 0; }
    __syncthreads();
    for (int i = t; i < NB_HE; i += 256) hh[i] = 0;
    for (int i = t; i < NB_ND; i += 256) hn[i] = 0;
    __syncthreads();
    for (int e = e0 + t; e < e0 + CHUNK; e += 256) {
        int s = src[e], d = dst[e];
        int bd = d >> 8, bs_ = s >> 8;
        int ph = bh[bd] + atomicAdd(&hh[bd], 1);
        bin_he[ph] = ((u32)(d & 255) << 24) | (u32)s;     // s < 2^17
        int pn = bn[bs_] + atomicAdd(&hn[bs_], 1);
        bin_nd[pn] = ((u32)(s & 255) << 24) | (u32)d;     // d < 2^15
    }
}

// ------- degrees from binned data -------------------------------------------
__global__ __launch_bounds__(256) void k_deg(const u32* __restrict__ bin_he, const u32* __restrict__ bin_nd,
                                             const int* __restrict__ start_he, const int* __restrict__ start_nd,
                                             int* __restrict__ deg_nd, int* __restrict__ deg_he) {
    __shared__ int cnt[256];
    int t = threadIdx.x, b = blockIdx.x;
    cnt[t] = 0; __syncthreads();
    if (b < NB_HE) {
        int lo = start_he[b], hi = start_he[b + 1];
        for (int j = lo + t; j < hi; j += 256) atomicAdd(&cnt[bin_he[j] >> 24], 1);
        __syncthreads();
        int id = b * 256 + t;
        if (id < N_HYPER) deg_he[id] = cnt[t];
    } else {
        int bb = b - NB_HE;
        int lo = start_nd[bb], hi = start_nd[bb + 1];
        for (int j = lo + t; j < hi; j += 256) atomicAdd(&cnt[bin_nd[j] >> 24], 1);
        __syncthreads();
        int id = bb * 256 + t;
        if (id < N_NODES) deg_nd[id] = cnt[t];
    }
}

// ------- multi-block scan, phase A: per-block sums --------------------------
__global__ __launch_bounds__(256) void k_scanA(const int* __restrict__ a_node,
                                               const int* __restrict__ a_he,
                                               int* __restrict__ bs) {
    __shared__ int red[256];
    int b = blockIdx.x;
    const int* a; int base, n;
    if (b < 25) { a = a_node; base = b * 4096; n = N_NODES; }
    else        { a = a_he;   base = (b - 25) * 4096; n = N_HYPER; }
    int t = threadIdx.x;
    int lo = base + t * 16;
    int s = 0;
#pragma unroll
    for (int i = 0; i < 16; ++i) {
        int idx = lo + i;
        if (idx < n) s += a[idx];
    }
    red[t] = s;
    __syncthreads();
    for (int off = 128; off > 0; off >>= 1) {
        if (t < off) red[t] += red[t + off];
        __syncthreads();
    }
    if (t == 0) bs[b] = red[0];
}

// ------- phase B: exclusive scan of the 25+5 block sums ---------------------
__global__ void k_scanB(int* __restrict__ bs) {
    int t = threadIdx.x;
    if (t == 0) {
        int run = 0;
        for (int i = 0; i < 25; ++i) { int v = bs[i]; bs[i] = run; run += v; }
    } else if (t == 1) {
        int run = 0;
        for (int i = 25; i < 30; ++i) { int v = bs[i]; bs[i] = run; run += v; }
    }
}

// ------- phase C: block-local scan + apply base; emit CSR starts + rsqrt ----
__global__ __launch_bounds__(256) void k_scanC(int* __restrict__ a_node, int* __restrict__ a_he,
                                               float* __restrict__ iq_node, float* __restrict__ iq_he,
                                               const int* __restrict__ bs) {
    __shared__ int pre[256];
    int b = blockIdx.x;
    int* a; float* iq; int base, n;
    if (b < 25) { a = a_node; iq = iq_node; base = b * 4096; n = N_NODES; }
    else        { a = a_he;   iq = iq_he;   base = (b - 25) * 4096; n = N_HYPER; }
    int t = threadIdx.x;
    int lo = base + t * 16;
    int loc = 0;
#pragma unroll
    for (int i = 0; i < 16; ++i) { int idx = lo + i; if (idx < n) loc += a[idx]; }
    pre[t] = loc;
    __syncthreads();
    for (int off = 1; off < 256; off <<= 1) {
        int v = (t >= off) ? pre[t - off] : 0;
        __syncthreads();
        pre[t] += v;
        __syncthreads();
    }
    int running = bs[b] + pre[t] - loc;   // global exclusive prefix for this thread
#pragma unroll
    for (int i = 0; i < 16; ++i) {
        int idx = lo + i;
        if (idx < n) {
            int d = a[idx];
            iq[idx] = rsqrtf((float)(d < 1 ? 1 : d));
            a[idx] = running;             // CSR segment START (sentinel set in k_bin_scan)
            running += d;
        }
    }
}

// ------- final CSR fill from bins: bucket-per-block, LDS base+rank ----------
__global__ __launch_bounds__(256) void k_fill2(const u32* __restrict__ bin_he, const u32* __restrict__ bin_nd,
                                               const int* __restrict__ start_he, const int* __restrict__ start_nd,
                                               const int* __restrict__ ptr_he, const int* __restrict__ ptr_node,
                                               int* __restrict__ adj_he, int* __restrict__ adj_node) {
    __shared__ int base[256], rk[256];
    int t = threadIdx.x, b = blockIdx.x;
    rk[t] = 0;
    if (b < NB_HE) {
        int id = b * 256 + t;
        base[t] = (id < N_HYPER) ? ptr_he[id] : 0;
        __syncthreads();
        int lo = start_he[b], hi = start_he[b + 1];
        for (int j = lo + t; j < hi; j += 256) {
            u32 v = bin_he[j];
            int lid = v >> 24;
            int pos = base[lid] + atomicAdd(&rk[lid], 1);
            adj_he[pos] = (int)(v & 0xFFFFFFu);
        }
    } else {
        int bb = b - NB_HE;
        int id = bb * 256 + t;
        base[t] = (id < N_NODES) ? ptr_node[id] : 0;
        __syncthreads();
        int lo = start_nd[bb], hi = start_nd[bb + 1];
        for (int j = lo + t; j < hi; j += 256) {
            u32 v = bin_nd[j];
            int lid = v >> 24;
            int pos = base[lid] + atomicAdd(&rk[lid], 1);
            adj_node[pos] = (int)(v & 0xFFFFFFu);
        }
    }
}

// ------- gather 1: acc1[d] = sum_{s in adj_he[d]} h_bf[s] * cn[s] -----------
__global__ __launch_bounds__(256) void k_gather1(const u16* __restrict__ h_bf,
                                                 const int* __restrict__ adj,
                                                 const int* __restrict__ ptr,
                                                 const float* __restrict__ cn,
                                                 float* __restrict__ acc1) {
    int row = blockIdx.x * 4 + (threadIdx.x >> 6);
    int lane = threadIdx.x & 63;
    int p = lane >> 5, c = lane & 31;
    int start = ptr[row];
    int end = ptr[row + 1];
    const uint2* hp = (const uint2*)h_bf;
    float A0[4] = {0, 0, 0, 0}, A1[4] = {0, 0, 0, 0};
    float f0, f1, f2, f3;
    int j = start;
    for (; j + 3 < end; j += 4) {
        int sA = adj[j + p], sB = adj[j + 2 + p];
        float wA = cn[sA], wB = cn[sB];
        uint2 vA = hp[sA * 32 + c];
        uint2 vB = hp[sB * 32 + c];
        bfu(vA.x, f0, f1); bfu(vA.y, f2, f3);
        A0[0] += f0 * wA; A0[1] += f1 * wA; A0[2] += f2 * wA; A0[3] += f3 * wA;
        bfu(vB.x, f0, f1); bfu(vB.y, f2, f3);
        A1[0] += f0 * wB; A1[1] += f1 * wB; A1[2] += f2 * wB; A1[3] += f3 * wB;
    }
    for (; j + 1 < end; j += 2) {
        int sA = adj[j + p];
        float wA = cn[sA];
        uint2 vA = hp[sA * 32 + c];
        bfu(vA.x, f0, f1); bfu(vA.y, f2, f3);
        A0[0] += f0 * wA; A0[1] += f1 * wA; A0[2] += f2 * wA; A0[3] += f3 * wA;
    }
    if (j < end && p == 0) {
        int sA = adj[j];
        float wA = cn[sA];
        uint2 vA = hp[sA * 32 + c];
        bfu(vA.x, f0, f1); bfu(vA.y, f2, f3);
        A0[0] += f0 * wA; A0[1] += f1 * wA; A0[2] += f2 * wA; A0[3] += f3 * wA;
    }
    float r0 = A0[0] + A1[0], r1 = A0[1] + A1[1], r2 = A0[2] + A1[2], r3 = A0[3] + A1[3];
    r0 += __shfl_xor(r0, 32, 64);
    r1 += __shfl_xor(r1, 32, 64);
    r2 += __shfl_xor(r2, 32, 64);
    r3 += __shfl_xor(r3, 32, 64);
    if (p == 0) {
        float4 o; o.x = r0; o.y = r1; o.z = r2; o.w = r3;
        ((float4*)acc1)[row * 32 + c] = o;
    }
}

// ------- gather 2: acc2[s] = sum_{d in adj_node[s]} hh2b[d] -----------------
__global__ __launch_bounds__(256) void k_gather2(const u16* __restrict__ hh2b,
                                                 const int* __restrict__ adj,
                                                 const int* __restrict__ ptr,
                                                 float* __restrict__ acc2) {
    int row = blockIdx.x * 4 + (threadIdx.x >> 6);
    int lane = threadIdx.x & 63;
    int p = lane >> 5, c = lane & 31;
    int start = ptr[row];
    int end = ptr[row + 1];
    const uint2* hp = (const uint2*)hh2b;
    float A0[4] = {0, 0, 0, 0}, A1[4] = {0, 0, 0, 0};
    float f0, f1, f2, f3;
    int j = start;
    for (; j + 3 < end; j += 4) {
        int dA = adj[j + p], dB = adj[j + 2 + p];
        uint2 vA = hp[dA * 32 + c];
        uint2 vB = hp[dB * 32 + c];
        bfu(vA.x, f0, f1); bfu(vA.y, f2, f3);
        A0[0] += f0; A0[1] += f1; A0[2] += f2; A0[3] += f3;
        bfu(vB.x, f0, f1); bfu(vB.y, f2, f3);
        A1[0] += f0; A1[1] += f1; A1[2] += f2; A1[3] += f3;
    }
    for (; j + 1 < end; j += 2) {
        int dA = adj[j + p];
        uint2 vA = hp[dA * 32 + c];
        bfu(vA.x, f0, f1); bfu(vA.y, f2, f3);
        A0[0] += f0; A0[1] += f1; A0[2] += f2; A0[3] += f3;
    }
    if (j < end && p == 0) {
        int dA = adj[j];
        uint2 vA = hp[dA * 32 + c];
        bfu(vA.x, f0, f1); bfu(vA.y, f2, f3);
        A0[0] += f0; A0[1] += f1; A0[2] += f2; A0[3] += f3;
    }
    float r0 = A0[0] + A1[0], r1 = A0[1] + A1[1], r2 = A0[2] + A1[2], r3 = A0[3] + A1[3];
    r0 += __shfl_xor(r0, 32, 64);
    r1 += __shfl_xor(r1, 32, 64);
    r2 += __shfl_xor(r2, 32, 64);
    r3 += __shfl_xor(r3, 32, 64);
    if (p == 0) {
        float4 o; o.x = r0; o.y = r1; o.z = r2; o.w = r3;
        ((float4*)acc2)[row * 32 + c] = o;
    }
}

// ------- GEMM1 (MFMA): hh2b = bf16(((acc1*ch) @ W1 + b1) * ch) --------------
__global__ __launch_bounds__(256) void k_gemm1(const float* __restrict__ a, const float* __restrict__ ch,
                                               const u16* __restrict__ W1t,
                                               const float* __restrict__ b1,
                                               u16* __restrict__ hh2b) {
    __shared__ u16 sA[64 * LDW];
    __shared__ u16 sW[128 * LDW];
    int tid = threadIdx.x;
    int r0 = blockIdx.x * 64;
    for (int i = tid; i < 64 * 32; i += 256) {
        int r = i >> 5, c4 = i & 31;
        int row = r0 + r; if (row > N_HYPER - 1) row = N_HYPER - 1;
        float4 v = *(const float4*)(a + row * 128 + c4 * 4);
        float cw = ch[row];
        u16* p = &sA[r * LDW + c4 * 4];
        p[0] = f2bf(v.x * cw); p[1] = f2bf(v.y * cw);
        p[2] = f2bf(v.z * cw); p[3] = f2bf(v.w * cw);
    }
    for (int i = tid; i < 128 * 16; i += 256) {
        int n = i >> 4, c = i & 15;
        *(uint4*)&sW[n * LDW + c * 8] = *(const uint4*)(W1t + n * 128 + c * 8);
    }
    __syncthreads();
    int w = tid >> 6, l15 = tid & 15, quad = (tid & 63) >> 4;
    f32x4 zero = {0.f, 0.f, 0.f, 0.f};
    f32x4 acc[8];
#pragma unroll
    for (int nt = 0; nt < 8; ++nt) acc[nt] = zero;
    int arow = w * 16 + l15;
#pragma unroll
    for (int kt = 0; kt < 4; ++kt) {
        bf16x8 af = *(bf16x8*)&sA[arow * LDW + kt * 32 + quad * 8];
#pragma unroll
        for (int nt = 0; nt < 8; ++nt) {
            bf16x8 bfv = *(bf16x8*)&sW[(nt * 16 + l15) * LDW + kt * 32 + quad * 8];
            acc[nt] = mfma16(af, bfv, acc[nt]);
        }
    }
#pragma unroll
    for (int r = 0; r < 4; ++r) {
        int row = r0 + w * 16 + quad * 4 + r;
        if (row < N_HYPER) {
            float cw = ch[row];
#pragma unroll
            for (int nt = 0; nt < 8; ++nt) {
                int n = nt * 16 + l15;
                hh2b[row * 128 + n] = f2bf((acc[nt][r] + b1[n]) * cw);
            }
        }
    }
}

// --- GEMM2 + residual + LN1 (MFMA, in-place): a := LN(h + (a*cn)@W2 + b2) ---
__global__ __launch_bounds__(256) void k_gemm2_ln(float* a, const float* __restrict__ cn,
                                                  const u16* __restrict__ W2t,
                                                  const float* __restrict__ b2,
                                                  const float* __restrict__ h,
                                                  const float* __restrict__ gamma1,
                                                  const float* __restrict__ beta1) {
    __shared__ u16 sA[64 * LDW];
    __shared__ u16 sW[128 * LDW];
    int tid = threadIdx.x;
    int r0 = blockIdx.x * 64;
    for (int i = tid; i < 64 * 32; i += 256) {
        int r = i >> 5, c4 = i & 31;
        int row = r0 + r; if (row > N_NODES - 1) row = N_NODES - 1;
        float4 v = *(const float4*)(a + row * 128 + c4 * 4);
        float cw = cn[row];
        u16* p = &sA[r * LDW + c4 * 4];
        p[0] = f2bf(v.x * cw); p[1] = f2bf(v.y * cw);
        p[2] = f2bf(v.z * cw); p[3] = f2bf(v.w * cw);
    }
    for (int i = tid; i < 128 * 16; i += 256) {
        int n = i >> 4, c = i & 15;
        *(uint4*)&sW[n * LDW + c * 8] = *(const uint4*)(W2t + n * 128 + c * 8);
    }
    __syncthreads();
    int w = tid >> 6, l15 = tid & 15, quad = (tid & 63) >> 4;
    f32x4 zero = {0.f, 0.f, 0.f, 0.f};
    f32x4 acc[8];
#pragma unroll
    for (int nt = 0; nt < 8; ++nt) acc[nt] = zero;
    int arow = w * 16 + l15;
#pragma unroll
    for (int kt = 0; kt < 4; ++kt) {
        bf16x8 af = *(bf16x8*)&sA[arow * LDW + kt * 32 + quad * 8];
#pragma unroll
        for (int nt = 0; nt < 8; ++nt) {
            bf16x8 bfv = *(bf16x8*)&sW[(nt * 16 + l15) * LDW + kt * 32 + quad * 8];
            acc[nt] = mfma16(af, bfv, acc[nt]);
        }
    }
    float s1[4] = {0, 0, 0, 0}, s2[4] = {0, 0, 0, 0};
#pragma unroll
    for (int r = 0; r < 4; ++r) {
        int row = r0 + w * 16 + quad * 4 + r;
        int rc = row > N_NODES - 1 ? N_NODES - 1 : row;
#pragma unroll
        for (int nt = 0; nt < 8; ++nt) {
            int n = nt * 16 + l15;
            float t = acc[nt][r] + b2[n] + h[rc * 128 + n];
            acc[nt][r] = t;
            s1[r] += t; s2[r] += t * t;
        }
    }
#pragma unroll
    for (int off = 1; off < 16; off <<= 1) {
#pragma unroll
        for (int r = 0; r < 4; ++r) {
            s1[r] += __shfl_xor(s1[r], off, 64);
            s2[r] += __shfl_xor(s2[r], off, 64);
        }
    }
#pragma unroll
    for (int r = 0; r < 4; ++r) {
        int row = r0 + w * 16 + quad * 4 + r;
        if (row < N_NODES) {
            float mu = s1[r] * (1.f / 128.f);
            float var = s2[r] * (1.f / 128.f) - mu * mu;
            float rs = rsqrtf(var + 1e-5f);
#pragma unroll
            for (int nt = 0; nt < 8; ++nt) {
                int n = nt * 16 + l15;
                a[row * 128 + n] = (acc[nt][r] - mu) * rs * gamma1[n] + beta1[n];
            }
        }
    }
}

// ------- FFN + residual + LN2: DMA weight pipeline + register A-tile --------
// Change vs round 9 (isolated): sA removed -- each thread's gemmA fragment is
// its own row/segment, so A lives in 4 loop-invariant bf16x8 regs. LDS drops
// 59.4 -> 42 KB => 3 blocks/CU (+50% TLP). vmcnt ordering: af loads issued
// FIRST (in-order retirement), DMAs pinned after via sched_barrier, so
// vmcnt(4) still isolates W3[0] (af+W3 retired, W4 flying).
__global__ __launch_bounds__(256) void k_ffn_ln(const float* __restrict__ h1,
                                                const u16* __restrict__ W3s,
                                                const float* __restrict__ b3,
                                                const u16* __restrict__ W4s,
                                                const float* __restrict__ b4,
                                                const float* __restrict__ gamma2,
                                                const float* __restrict__ beta2,
                                                float* __restrict__ out) {
    __shared__ __align__(16) u16 sY[64 * LDY];   //  9.2 KB (wave-private rows)
    __shared__ __align__(16) u16 sW3[8192];      // 16 KB linear W3 chunk
    __shared__ __align__(16) u16 sW4[8192];      // 16 KB linear W4 chunk
    int tid = threadIdx.x;
    int w = tid >> 6, lane = tid & 63;
    int l15 = tid & 15, quad = (tid & 63) >> 4;
    int r0 = blockIdx.x * 64;
    int dmaoff = w * 4096 + lane * 16;           // bytes; +j*1024 per call

    // 1) A-fragment loads FIRST (oldest in vmcnt order)
    int arow_g = r0 + w * 16 + l15; if (arow_g > N_NODES - 1) arow_g = N_NODES - 1;
    const float* ap = h1 + arow_g * 128 + quad * 8;
    float4 av0[4], av1[4];
#pragma unroll
    for (int kt = 0; kt < 4; ++kt) {
        av0[kt] = *(const float4*)(ap + kt * 32);
        av1[kt] = *(const float4*)(ap + kt * 32 + 4);
    }
    __builtin_amdgcn_sched_barrier(0);
    // 2) fire DMA for W3[0] and W4[0]
#pragma unroll
    for (int j = 0; j < 4; ++j)
        dma16((const u16*)((const char*)W3s + dmaoff + j * 1024),
              (u16*)((char*)sW3 + w * 4096 + j * 1024));
#pragma unroll
    for (int j = 0; j < 4; ++j)
        dma16((const u16*)((const char*)W4s + dmaoff + j * 1024),
              (u16*)((char*)sW4 + w * 4096 + j * 1024));
    __builtin_amdgcn_sched_barrier(0);
    // 3) convert to bf16 fragments (VALU covers DMA flight)
    bf16x8 af[4];
#pragma unroll
    for (int kt = 0; kt < 4; ++kt) {
        bf16x8 t;
        t[0] = (short)f2bf(av0[kt].x); t[1] = (short)f2bf(av0[kt].y);
        t[2] = (short)f2bf(av0[kt].z); t[3] = (short)f2bf(av0[kt].w);
        t[4] = (short)f2bf(av1[kt].x); t[5] = (short)f2bf(av1[kt].y);
        t[6] = (short)f2bf(av1[kt].z); t[7] = (short)f2bf(av1[kt].w);
        af[kt] = t;
    }
    asm volatile("s_waitcnt vmcnt(4)" ::: "memory");  // af+W3[0] retired; W4[0] flying
    __builtin_amdgcn_s_barrier();
    __builtin_amdgcn_sched_barrier(0);

    int arow = w * 16 + l15;
    f32x4 zero = {0.f, 0.f, 0.f, 0.f};
    f32x4 acc[8];
#pragma unroll
    for (int nt = 0; nt < 8; ++nt) acc[nt] = zero;

    for (int hc = 0; hc < 8; ++hc) {
        // gemmA: Y[16x64/wave] = af @ W3chunk (swizzled read)
        f32x4 y[4];
#pragma unroll
        for (int nt = 0; nt < 4; ++nt) y[nt] = zero;
#pragma unroll
        for (int kt = 0; kt < 4; ++kt) {
#pragma unroll
            for (int nt = 0; nt < 4; ++nt) {
                int r = nt * 16 + l15;
                bf16x8 bv = *(bf16x8*)&sW3[r * 128 + ((((kt << 2) + quad) ^ l15) << 3)];
                y[nt] = mfma16(af[kt], bv, y[nt]);
            }
        }
        // bias + relu -> sY (wave-private rows)
#pragma unroll
        for (int r = 0; r < 4; ++r) {
            int yrow = w * 16 + quad * 4 + r;
#pragma unroll
            for (int nt = 0; nt < 4; ++nt) {
                int n = nt * 16 + l15;
                float vv = y[nt][r] + b3[hc * 64 + n];
                sY[yrow * LDY + n] = f2bf(vv > 0.f ? vv : 0.f);
            }
        }
        __builtin_amdgcn_s_barrier();            // all done reading sW3[hc]
        __builtin_amdgcn_sched_barrier(0);
        {   // DMA W3[next] (dummy wrap at hc==7 keeps vmcnt counting uniform)
            const char* g3 = (const char*)W3s + ((hc + 1) & 7) * 16384;
#pragma unroll
            for (int j = 0; j < 4; ++j)
                dma16((const u16*)(g3 + dmaoff + j * 1024),
                      (u16*)((char*)sW3 + w * 4096 + j * 1024));
        }
        asm volatile("s_waitcnt vmcnt(4)" ::: "memory");  // own W4[hc] arrived
        __builtin_amdgcn_s_barrier();            // everyone's W4[hc] visible
        __builtin_amdgcn_sched_barrier(0);
        // gemmB: acc += Y @ W4chunk (K=64, swizzled read)
#pragma unroll
        for (int kt = 0; kt < 2; ++kt) {
            bf16x8 ay = *(bf16x8*)&sY[arow * LDY + kt * 32 + quad * 8];
#pragma unroll
            for (int nt = 0; nt < 8; ++nt) {
                int rr = nt * 16 + l15;
                bf16x8 bv = *(bf16x8*)&sW4[rr * 64 + ((((kt << 2) + quad) ^ (l15 & 7)) << 3)];
                acc[nt] = mfma16(ay, bv, acc[nt]);
            }
        }
        if (hc == 7) break;
        __builtin_amdgcn_s_barrier();            // all done reading sW4[hc]
        __builtin_amdgcn_sched_barrier(0);
        {   // DMA W4[hc+1]
            const char* g4 = (const char*)W4s + (hc + 1) * 16384;
#pragma unroll
            for (int j = 0; j < 4; ++j)
                dma16((const u16*)(g4 + dmaoff + j * 1024),
                      (u16*)((char*)sW4 + w * 4096 + j * 1024));
        }
        asm volatile("s_waitcnt vmcnt(4)" ::: "memory");  // own W3[hc+1] arrived
        __builtin_amdgcn_s_barrier();            // everyone's W3[hc+1] visible
        __builtin_amdgcn_sched_barrier(0);
    }
    // epilogue: residual + LN2 (round-4 proven)
    float s1[4] = {0, 0, 0, 0}, s2[4] = {0, 0, 0, 0};
#pragma unroll
    for (int r = 0; r < 4; ++r) {
        int row = r0 + w * 16 + quad * 4 + r;
        int rc = row > N_NODES - 1 ? N_NODES - 1 : row;
#pragma unroll
        for (int nt = 0; nt < 8; ++nt) {
            int n = nt * 16 + l15;
            float t = acc[nt][r] + b4[n] + h1[rc * 128 + n];
            acc[nt][r] = t;
            s1[r] += t; s2[r] += t * t;
        }
    }
#pragma unroll
    for (int off = 1; off < 16; off <<= 1) {
#pragma unroll
        for (int r = 0; r < 4; ++r) {
            s1[r] += __shfl_xor(s1[r], off, 64);
            s2[r] += __shfl_xor(s2[r], off, 64);
        }
    }
#pragma unroll
    for (int r = 0; r < 4; ++r) {
        int row = r0 + w * 16 + quad * 4 + r;
        if (row < N_NODES) {
            float mu = s1[r] * (1.f / 128.f);
            float var = s2[r] * (1.f / 128.f) - mu * mu;
            float rs = rsqrtf(var + 1e-5f);
#pragma unroll
            for (int nt = 0; nt < 8; ++nt) {
                int n = nt * 16 + l15;
                out[row * 128 + n] = (acc[nt][r] - mu) * rs * gamma2[n] + beta2[n];
            }
        }
    }
}

extern "C" void kernel_launch(void* const* d_in, const int* in_sizes, int n_in,
                              void* d_out, int out_size, void* d_ws, size_t ws_size,
                              hipStream_t stream) {
    const float* h      = (const float*)d_in[0];
    const int*   src    = (const int*)d_in[1];
    const int*   dst    = (const int*)d_in[2];
    const float* W1     = (const float*)d_in[3];
    const float* b1     = (const float*)d_in[4];
    const float* W2     = (const float*)d_in[5];
    const float* b2     = (const float*)d_in[6];
    const float* W3     = (const float*)d_in[7];
    const float* b3     = (const float*)d_in[8];
    const float* W4     = (const float*)d_in[9];
    const float* b4     = (const float*)d_in[10];
    const float* gamma1 = (const float*)d_in[11];
    const float* beta1  = (const float*)d_in[12];
    const float* gamma2 = (const float*)d_in[13];
    const float* beta2  = (const float*)d_in[14];
    float* out = (float*)d_out;

    // ws layout (bytes), with dead-region aliasing (same as round 4):
    char* ws = (char*)d_ws;
    int*   ptr_node = (int*)(ws + 0);
    int*   ptr_he   = (int*)(ws + 400512);
    int*   adj_he   = (int*)(ws + 481280);
    int*   adj_node = (int*)(ws + 6881280);
    float* cn       = (float*)(ws + 13281280);
    float* ch       = (float*)(ws + 13681280);
    u16*   h_bf     = (u16*)(ws + 24000000);
    u32*   bin_he   = (u32*)(ws + 49600000);
    u32*   bin_nd   = (u32*)(ws + 56000000);
    float* acc1     = (float*)(ws + 62400000);
    int*   bkt_he   = (int*)(ws + 72640000);
    int*   bkt_nd   = (int*)(ws + 72640512);
    int*   start_he = (int*)(ws + 72642560);
    int*   start_nd = (int*)(ws + 72643072);
    int*   bs       = (int*)(ws + 72644864);
    float* acc2     = (float*)(ws + 24000000);
    u16*   hh2b     = (u16*)(ws + 481280);     // alias adj_he (dead after gather1)
    u16*   W1t      = (u16*)(ws + 75200000);
    u16*   W2t      = (u16*)(ws + 75232768);
    u16*   W3t      = (u16*)(ws + 75265536);
    u16*   W4t      = (u16*)(ws + 75396608);

    hipMemsetAsync(ws + 72640000, 0, 2560, stream);   // zero bucket counters only

    k_prep<<<12800, 256, 0, stream>>>(W1, W2, W3, W4, W1t, W2t, W3t, W4t, h, h_bf);
    k_bin_hist<<<256, 256, 0, stream>>>(src, dst, bkt_he, bkt_nd);
    k_bin_scan<<<1, 512, 0, stream>>>(bkt_he, bkt_nd, start_he, start_nd, ptr_node, ptr_he);
    k_bin_fill<<<256, 256, 0, stream>>>(src, dst, bkt_he, bkt_nd, bin_he, bin_nd);
    k_deg<<<NB_HE + NB_ND, 256, 0, stream>>>(bin_he, bin_nd, start_he, start_nd, ptr_node, ptr_he);
    k_scanA<<<30, 256, 0, stream>>>(ptr_node, ptr_he, bs);
    k_scanB<<<1, 64, 0, stream>>>(bs);
    k_scanC<<<30, 256, 0, stream>>>(ptr_node, ptr_he, cn, ch, bs);
    k_fill2<<<NB_HE + NB_ND, 256, 0, stream>>>(bin_he, bin_nd, start_he, start_nd,
                                               ptr_he, ptr_node, adj_he, adj_node);
    k_gather1<<<5000, 256, 0, stream>>>(h_bf, adj_he, ptr_he, cn, acc1);
    k_gemm1<<<313, 256, 0, stream>>>(acc1, ch, W1t, b1, hh2b);
    k_gather2<<<25000, 256, 0, stream>>>(hh2b, adj_node, ptr_node, acc2);
    k_gemm2_ln<<<1563, 256, 0, stream>>>(acc2, cn, W2t, b2, h, gamma1, beta1);
    k_ffn_ln<<<1563, 256, 0, stream>>>(acc2, W3t, b3, W4t, b4, gamma2, beta2, out);
}

// Round 12
// 463.587 us; speedup vs baseline: 1.1118x; 1.0265x over previous
//
#include <hip/hip_runtime.h>

#define N_NODES 100000
#define N_HYPER 20000
#define N_EDGES 1600000
#define LDW 136   // LDS row stride in bf16 elems: 272 B = odd*16B (16B-aligned, bank-decorrelated)
#define LDY 72    // row stride for 64-col tiles: 144 B, same bank-rotation property

#define NB_HE 79      // ceil(20000/256) hyperedge buckets (id >> 8)
#define NB_ND 391     // ceil(100000/256) node buckets (id >> 8)
#define CAP_HE 24576  // fixed bucket capacity (mean 20480, sigma~142 -> +28 sigma)
#define CAP_ND 5120   // fixed bucket capacity (mean 4096, sigma~64 -> +16 sigma)
#define FCHUNK 2000   // edges per binning block: 800 * 2000 = 1.6M exactly

typedef unsigned short u16;
typedef unsigned int u32;
typedef short bf16x8 __attribute__((ext_vector_type(8)));
typedef float f32x4 __attribute__((ext_vector_type(4)));

typedef __attribute__((address_space(3))) unsigned int lds_u32;
typedef __attribute__((address_space(1))) unsigned int gbl_u32;

__device__ __forceinline__ f32x4 mfma16(bf16x8 a, bf16x8 b, f32x4 c) {
    return __builtin_amdgcn_mfma_f32_16x16x32_bf16(a, b, c, 0, 0, 0);
}
__device__ __forceinline__ u16 f2bf(float f) {
    unsigned u = __float_as_uint(f);
    unsigned r = u + 0x7FFFu + ((u >> 16) & 1u);   // RN-even
    return (u16)(r >> 16);
}
__device__ __forceinline__ void bfu(unsigned v, float& f0, float& f1) {
    f0 = __uint_as_float(v << 16);
    f1 = __uint_as_float(v & 0xFFFF0000u);
}
// async DMA global->LDS, 16B per lane; lds dest = wave-uniform base + lane*16
__device__ __forceinline__ void dma16(const u16* g, u16* l) {
    __builtin_amdgcn_global_load_lds((const gbl_u32*)(const void*)g,
                                     (lds_u32*)(void*)l, 16, 0, 0);
}

// ------- weight prep: W1/W2 plain; W3/W4 chunked+XOR-swizzled for DMA -------
// W3s: 8 chunks of [64 rows n][128 k] bf16, 16KB each; granule g=k>>3 stored
// at g^(nn&15). W4s: 8 chunks of [128 rows n4][64 kk]; g=kk>>3 at g^(n4&7).
__global__ __launch_bounds__(256) void k_prep(const float* __restrict__ W1, const float* __restrict__ W2,
                                              const float* __restrict__ W3, const float* __restrict__ W4,
                                              u16* __restrict__ W1t, u16* __restrict__ W2t,
                                              u16* __restrict__ W3t, u16* __restrict__ W4t,
                                              const float* __restrict__ h, u16* __restrict__ h_bf) {
    int i = blockIdx.x * 256 + threadIdx.x;
    if (i < 16384) {
        int k = i & 127, n = i >> 7;
        W1t[n * 128 + k] = f2bf(W1[k * 128 + n]);
        W2t[n * 128 + k] = f2bf(W2[k * 128 + n]);
    }
    if (i < 65536) {
        int k = i & 127, n = i >> 7;          // n < 512 hidden
        int hc = n >> 6, nn = n & 63;
        int g3 = (k >> 3) ^ (nn & 15);
        W3t[hc * 8192 + nn * 128 + g3 * 8 + (k & 7)] = f2bf(W3[k * 512 + n]);
        int k4 = i & 511, n4 = i >> 9;        // n4 < 128 out-col, k4 < 512 hidden
        int hc4 = k4 >> 6, kk = k4 & 63;
        int g4 = (kk >> 3) ^ (n4 & 7);
        W4t[hc4 * 8192 + n4 * 64 + g4 * 8 + (kk & 7)] = f2bf(W4[k4 * 128 + n4]);
    }
    if (i < 3276800) {                        // 12.8M elems / 4
        float4 v = ((const float4*)h)[i];
        uint2 st;
        st.x = (u32)f2bf(v.x) | ((u32)f2bf(v.y) << 16);
        st.y = (u32)f2bf(v.z) | ((u32)f2bf(v.w) << 16);
        ((uint2*)h_bf)[i] = st;
    }
}

// ------- binning (single pass): LDS hist -> fixed-cap bucket reservation ----
// Fixed-capacity buckets eliminate the global histogram + bucket scan: block
// reserves a contiguous run in bucket i at i*CAP + atomicAdd(&bkt[i], c).
__global__ __launch_bounds__(256) void k_bin_fill(const int* __restrict__ src, const int* __restrict__ dst,
                                                  int* __restrict__ bkt_he, int* __restrict__ bkt_nd,
                                                  u32* __restrict__ bin_he, u32* __restrict__ bin_nd) {
    __shared__ int hh[NB_HE], hn[NB_ND], bh[NB_HE], bn[NB_ND];
    int t = threadIdx.x;
    for (int i = t; i < NB_HE; i += 256) hh[i] = 0;
    for (int i = t; i < NB_ND; i += 256) hn[i] = 0;
    __syncthreads();
    int e0 = blockIdx.x * FCHUNK;
    for (int e = e0 + t; e < e0 + FCHUNK; e += 256) {
        atomicAdd(&hn[src[e] >> 8], 1);
        atomicAdd(&hh[dst[e] >> 8], 1);
    }
    __syncthreads();
    for (int i = t; i < NB_HE; i += 256) {
        int c = hh[i];
        bh[i] = (c ? atomicAdd(&bkt_he[i], c) : 0) + i * CAP_HE;
    }
    for (int i = t; i < NB_ND; i += 256) {
        int c = hn[i];
        bn[i] = (c ? atomicAdd(&bkt_nd[i], c) : 0) + i * CAP_ND;
    }
    __syncthreads();
    for (int i = t; i < NB_HE; i += 256) hh[i] = 0;
    for (int i = t; i < NB_ND; i += 256) hn[i] = 0;
    __syncthreads();
    for (int e = e0 + t; e < e0 + FCHUNK; e += 256) {
        int s = src[e], d = dst[e];
        int bd = d >> 8, bs_ = s >> 8;
        int ph = bh[bd] + atomicAdd(&hh[bd], 1);
        bin_he[ph] = ((u32)(d & 255) << 24) | (u32)s;     // s < 2^17
        int pn = bn[bs_] + atomicAdd(&hn[bs_], 1);
        bin_nd[pn] = ((u32)(s & 255) << 24) | (u32)d;     // d < 2^15
    }
}

// ------- degrees from binned data (fixed-cap bucket ranges) -----------------
__global__ __launch_bounds__(256) void k_deg(const u32* __restrict__ bin_he, const u32* __restrict__ bin_nd,
                                             const int* __restrict__ bkt_he, const int* __restrict__ bkt_nd,
                                             int* __restrict__ deg_nd, int* __restrict__ deg_he) {
    __shared__ int cnt[256];
    int t = threadIdx.x, b = blockIdx.x;
    cnt[t] = 0; __syncthreads();
    if (b < NB_HE) {
        int lo = b * CAP_HE, hi = lo + bkt_he[b];
        for (int j = lo + t; j < hi; j += 256) atomicAdd(&cnt[bin_he[j] >> 24], 1);
        __syncthreads();
        int id = b * 256 + t;
        if (id < N_HYPER) deg_he[id] = cnt[t];
    } else {
        int bb = b - NB_HE;
        int lo = bb * CAP_ND, hi = lo + bkt_nd[bb];
        for (int j = lo + t; j < hi; j += 256) atomicAdd(&cnt[bin_nd[j] >> 24], 1);
        __syncthreads();
        int id = bb * 256 + t;
        if (id < N_NODES) deg_nd[id] = cnt[t];
    }
}

// ------- multi-block scan, phase A: per-block sums --------------------------
__global__ __launch_bounds__(256) void k_scanA(const int* __restrict__ a_node,
                                               const int* __restrict__ a_he,
                                               int* __restrict__ bs) {
    __shared__ int red[256];
    int b = blockIdx.x;
    const int* a; int base, n;
    if (b < 25) { a = a_node; base = b * 4096; n = N_NODES; }
    else        { a = a_he;   base = (b - 25) * 4096; n = N_HYPER; }
    int t = threadIdx.x;
    int lo = base + t * 16;
    int s = 0;
#pragma unroll
    for (int i = 0; i < 16; ++i) {
        int idx = lo + i;
        if (idx < n) s += a[idx];
    }
    red[t] = s;
    __syncthreads();
    for (int off = 128; off > 0; off >>= 1) {
        if (t < off) red[t] += red[t + off];
        __syncthreads();
    }
    if (t == 0) bs[b] = red[0];
}

// ------- phase B: exclusive scan of the 25+5 block sums + CSR sentinels -----
__global__ void k_scanB(int* __restrict__ bs, int* __restrict__ ptr_node, int* __restrict__ ptr_he) {
    int t = threadIdx.x;
    if (t == 0) {
        int run = 0;
        for (int i = 0; i < 25; ++i) { int v = bs[i]; bs[i] = run; run += v; }
    } else if (t == 1) {
        int run = 0;
        for (int i = 25; i < 30; ++i) { int v = bs[i]; bs[i] = run; run += v; }
    } else if (t == 2) {
        ptr_node[N_NODES] = N_EDGES;
        ptr_he[N_HYPER] = N_EDGES;
    }
}

// ------- phase C: block-local scan + apply base; emit CSR starts + rsqrt ----
__global__ __launch_bounds__(256) void k_scanC(int* __restrict__ a_node, int* __restrict__ a_he,
                                               float* __restrict__ iq_node, float* __restrict__ iq_he,
                                               const int* __restrict__ bs) {
    __shared__ int pre[256];
    int b = blockIdx.x;
    int* a; float* iq; int base, n;
    if (b < 25) { a = a_node; iq = iq_node; base = b * 4096; n = N_NODES; }
    else        { a = a_he;   iq = iq_he;   base = (b - 25) * 4096; n = N_HYPER; }
    int t = threadIdx.x;
    int lo = base + t * 16;
    int loc = 0;
#pragma unroll
    for (int i = 0; i < 16; ++i) { int idx = lo + i; if (idx < n) loc += a[idx]; }
    pre[t] = loc;
    __syncthreads();
    for (int off = 1; off < 256; off <<= 1) {
        int v = (t >= off) ? pre[t - off] : 0;
        __syncthreads();
        pre[t] += v;
        __syncthreads();
    }
    int running = bs[b] + pre[t] - loc;   // global exclusive prefix for this thread
#pragma unroll
    for (int i = 0; i < 16; ++i) {
        int idx = lo + i;
        if (idx < n) {
            int d = a[idx];
            iq[idx] = rsqrtf((float)(d < 1 ? 1 : d));
            a[idx] = running;             // CSR segment START (sentinel set in k_scanB)
            running += d;
        }
    }
}

// ------- final CSR fill from bins: bucket-per-block, LDS base+rank ----------
__global__ __launch_bounds__(256) void k_fill2(const u32* __restrict__ bin_he, const u32* __restrict__ bin_nd,
                                               const int* __restrict__ bkt_he, const int* __restrict__ bkt_nd,
                                               const int* __restrict__ ptr_he, const int* __restrict__ ptr_node,
                                               int* __restrict__ adj_he, int* __restrict__ adj_node) {
    __shared__ int base[256], rk[256];
    int t = threadIdx.x, b = blockIdx.x;
    rk[t] = 0;
    if (b < NB_HE) {
        int id = b * 256 + t;
        base[t] = (id < N_HYPER) ? ptr_he[id] : 0;
        __syncthreads();
        int lo = b * CAP_HE, hi = lo + bkt_he[b];
        for (int j = lo + t; j < hi; j += 256) {
            u32 v = bin_he[j];
            int lid = v >> 24;
            int pos = base[lid] + atomicAdd(&rk[lid], 1);
            adj_he[pos] = (int)(v & 0xFFFFFFu);
        }
    } else {
        int bb = b - NB_HE;
        int id = bb * 256 + t;
        base[t] = (id < N_NODES) ? ptr_node[id] : 0;
        __syncthreads();
        int lo = bb * CAP_ND, hi = lo + bkt_nd[bb];
        for (int j = lo + t; j < hi; j += 256) {
            u32 v = bin_nd[j];
            int lid = v >> 24;
            int pos = base[lid] + atomicAdd(&rk[lid], 1);
            adj_node[pos] = (int)(v & 0xFFFFFFu);
        }
    }
}

// ------- gather 1: acc1[d] = sum_{s in adj_he[d]} h_bf[s] * cn[s] -----------
__global__ __launch_bounds__(256) void k_gather1(const u16* __restrict__ h_bf,
                                                 const int* __restrict__ adj,
                                                 const int* __restrict__ ptr,
                                                 const float* __restrict__ cn,
                                                 float* __restrict__ acc1) {
    int row = blockIdx.x * 4 + (threadIdx.x >> 6);
    int lane = threadIdx.x & 63;
    int p = lane >> 5, c = lane & 31;
    int start = ptr[row];
    int end = ptr[row + 1];
    const uint2* hp = (const uint2*)h_bf;
    float A0[4] = {0, 0, 0, 0}, A1[4] = {0, 0, 0, 0};
    float f0, f1, f2, f3;
    int j = start;
    for (; j + 3 < end; j += 4) {
        int sA = adj[j + p], sB = adj[j + 2 + p];
        float wA = cn[sA], wB = cn[sB];
        uint2 vA = hp[sA * 32 + c];
        uint2 vB = hp[sB * 32 + c];
        bfu(vA.x, f0, f1); bfu(vA.y, f2, f3);
        A0[0] += f0 * wA; A0[1] += f1 * wA; A0[2] += f2 * wA; A0[3] += f3 * wA;
        bfu(vB.x, f0, f1); bfu(vB.y, f2, f3);
        A1[0] += f0 * wB; A1[1] += f1 * wB; A1[2] += f2 * wB; A1[3] += f3 * wB;
    }
    for (; j + 1 < end; j += 2) {
        int sA = adj[j + p];
        float wA = cn[sA];
        uint2 vA = hp[sA * 32 + c];
        bfu(vA.x, f0, f1); bfu(vA.y, f2, f3);
        A0[0] += f0 * wA; A0[1] += f1 * wA; A0[2] += f2 * wA; A0[3] += f3 * wA;
    }
    if (j < end && p == 0) {
        int sA = adj[j];
        float wA = cn[sA];
        uint2 vA = hp[sA * 32 + c];
        bfu(vA.x, f0, f1); bfu(vA.y, f2, f3);
        A0[0] += f0 * wA; A0[1] += f1 * wA; A0[2] += f2 * wA; A0[3] += f3 * wA;
    }
    float r0 = A0[0] + A1[0], r1 = A0[1] + A1[1], r2 = A0[2] + A1[2], r3 = A0[3] + A1[3];
    r0 += __shfl_xor(r0, 32, 64);
    r1 += __shfl_xor(r1, 32, 64);
    r2 += __shfl_xor(r2, 32, 64);
    r3 += __shfl_xor(r3, 32, 64);
    if (p == 0) {
        float4 o; o.x = r0; o.y = r1; o.z = r2; o.w = r3;
        ((float4*)acc1)[row * 32 + c] = o;
    }
}

// ------- gather 2: acc2[s] = sum_{d in adj_node[s]} hh2b[d] -----------------
__global__ __launch_bounds__(256) void k_gather2(const u16* __restrict__ hh2b,
                                                 const int* __restrict__ adj,
                                                 const int* __restrict__ ptr,
                                                 float* __restrict__ acc2) {
    int row = blockIdx.x * 4 + (threadIdx.x >> 6);
    int lane = threadIdx.x & 63;
    int p = lane >> 5, c = lane & 31;
    int start = ptr[row];
    int end = ptr[row + 1];
    const uint2* hp = (const uint2*)hh2b;
    float A0[4] = {0, 0, 0, 0}, A1[4] = {0, 0, 0, 0};
    float f0, f1, f2, f3;
    int j = start;
    for (; j + 3 < end; j += 4) {
        int dA = adj[j + p], dB = adj[j + 2 + p];
        uint2 vA = hp[dA * 32 + c];
        uint2 vB = hp[dB * 32 + c];
        bfu(vA.x, f0, f1); bfu(vA.y, f2, f3);
        A0[0] += f0; A0[1] += f1; A0[2] += f2; A0[3] += f3;
        bfu(vB.x, f0, f1); bfu(vB.y, f2, f3);
        A1[0] += f0; A1[1] += f1; A1[2] += f2; A1[3] += f3;
    }
    for (; j + 1 < end; j += 2) {
        int dA = adj[j + p];
        uint2 vA = hp[dA * 32 + c];
        bfu(vA.x, f0, f1); bfu(vA.y, f2, f3);
        A0[0] += f0; A0[1] += f1; A0[2] += f2; A0[3] += f3;
    }
    if (j < end && p == 0) {
        int dA = adj[j];
        uint2 vA = hp[dA * 32 + c];
        bfu(vA.x, f0, f1); bfu(vA.y, f2, f3);
        A0[0] += f0; A0[1] += f1; A0[2] += f2; A0[3] += f3;
    }
    float r0 = A0[0] + A1[0], r1 = A0[1] + A1[1], r2 = A0[2] + A1[2], r3 = A0[3] + A1[3];
    r0 += __shfl_xor(r0, 32, 64);
    r1 += __shfl_xor(r1, 32, 64);
    r2 += __shfl_xor(r2, 32, 64);
    r3 += __shfl_xor(r3, 32, 64);
    if (p == 0) {
        float4 o; o.x = r0; o.y = r1; o.z = r2; o.w = r3;
        ((float4*)acc2)[row * 32 + c] = o;
    }
}

// ------- GEMM1 (MFMA): hh2b = bf16(((acc1*ch) @ W1 + b1) * ch) --------------
__global__ __launch_bounds__(256) void k_gemm1(const float* __restrict__ a, const float* __restrict__ ch,
                                               const u16* __restrict__ W1t,
                                               const float* __restrict__ b1,
                                               u16* __restrict__ hh2b) {
    __shared__ u16 sA[64 * LDW];
    __shared__ u16 sW[128 * LDW];
    int tid = threadIdx.x;
    int r0 = blockIdx.x * 64;
    for (int i = tid; i < 64 * 32; i += 256) {
        int r = i >> 5, c4 = i & 31;
        int row = r0 + r; if (row > N_HYPER - 1) row = N_HYPER - 1;
        float4 v = *(const float4*)(a + row * 128 + c4 * 4);
        float cw = ch[row];
        u16* p = &sA[r * LDW + c4 * 4];
        p[0] = f2bf(v.x * cw); p[1] = f2bf(v.y * cw);
        p[2] = f2bf(v.z * cw); p[3] = f2bf(v.w * cw);
    }
    for (int i = tid; i < 128 * 16; i += 256) {
        int n = i >> 4, c = i & 15;
        *(uint4*)&sW[n * LDW + c * 8] = *(const uint4*)(W1t + n * 128 + c * 8);
    }
    __syncthreads();
    int w = tid >> 6, l15 = tid & 15, quad = (tid & 63) >> 4;
    f32x4 zero = {0.f, 0.f, 0.f, 0.f};
    f32x4 acc[8];
#pragma unroll
    for (int nt = 0; nt < 8; ++nt) acc[nt] = zero;
    int arow = w * 16 + l15;
#pragma unroll
    for (int kt = 0; kt < 4; ++kt) {
        bf16x8 af = *(bf16x8*)&sA[arow * LDW + kt * 32 + quad * 8];
#pragma unroll
        for (int nt = 0; nt < 8; ++nt) {
            bf16x8 bfv = *(bf16x8*)&sW[(nt * 16 + l15) * LDW + kt * 32 + quad * 8];
            acc[nt] = mfma16(af, bfv, acc[nt]);
        }
    }
#pragma unroll
    for (int r = 0; r < 4; ++r) {
        int row = r0 + w * 16 + quad * 4 + r;
        if (row < N_HYPER) {
            float cw = ch[row];
#pragma unroll
            for (int nt = 0; nt < 8; ++nt) {
                int n = nt * 16 + l15;
                hh2b[row * 128 + n] = f2bf((acc[nt][r] + b1[n]) * cw);
            }
        }
    }
}

// --- GEMM2 + residual + LN1 (MFMA, in-place): a := LN(h + (a*cn)@W2 + b2) ---
__global__ __launch_bounds__(256) void k_gemm2_ln(float* a, const float* __restrict__ cn,
                                                  const u16* __restrict__ W2t,
                                                  const float* __restrict__ b2,
                                                  const float* __restrict__ h,
                                                  const float* __restrict__ gamma1,
                                                  const float* __restrict__ beta1) {
    __shared__ u16 sA[64 * LDW];
    __shared__ u16 sW[128 * LDW];
    int tid = threadIdx.x;
    int r0 = blockIdx.x * 64;
    for (int i = tid; i < 64 * 32; i += 256) {
        int r = i >> 5, c4 = i & 31;
        int row = r0 + r; if (row > N_NODES - 1) row = N_NODES - 1;
        float4 v = *(const float4*)(a + row * 128 + c4 * 4);
        float cw = cn[row];
        u16* p = &sA[r * LDW + c4 * 4];
        p[0] = f2bf(v.x * cw); p[1] = f2bf(v.y * cw);
        p[2] = f2bf(v.z * cw); p[3] = f2bf(v.w * cw);
    }
    for (int i = tid; i < 128 * 16; i += 256) {
        int n = i >> 4, c = i & 15;
        *(uint4*)&sW[n * LDW + c * 8] = *(const uint4*)(W2t + n * 128 + c * 8);
    }
    __syncthreads();
    int w = tid >> 6, l15 = tid & 15, quad = (tid & 63) >> 4;
    f32x4 zero = {0.f, 0.f, 0.f, 0.f};
    f32x4 acc[8];
#pragma unroll
    for (int nt = 0; nt < 8; ++nt) acc[nt] = zero;
    int arow = w * 16 + l15;
#pragma unroll
    for (int kt = 0; kt < 4; ++kt) {
        bf16x8 af = *(bf16x8*)&sA[arow * LDW + kt * 32 + quad * 8];
#pragma unroll
        for (int nt = 0; nt < 8; ++nt) {
            bf16x8 bfv = *(bf16x8*)&sW[(nt * 16 + l15) * LDW + kt * 32 + quad * 8];
            acc[nt] = mfma16(af, bfv, acc[nt]);
        }
    }
    float s1[4] = {0, 0, 0, 0}, s2[4] = {0, 0, 0, 0};
#pragma unroll
    for (int r = 0; r < 4; ++r) {
        int row = r0 + w * 16 + quad * 4 + r;
        int rc = row > N_NODES - 1 ? N_NODES - 1 : row;
#pragma unroll
        for (int nt = 0; nt < 8; ++nt) {
            int n = nt * 16 + l15;
            float t = acc[nt][r] + b2[n] + h[rc * 128 + n];
            acc[nt][r] = t;
            s1[r] += t; s2[r] += t * t;
        }
    }
#pragma unroll
    for (int off = 1; off < 16; off <<= 1) {
#pragma unroll
        for (int r = 0; r < 4; ++r) {
            s1[r] += __shfl_xor(s1[r], off, 64);
            s2[r] += __shfl_xor(s2[r], off, 64);
        }
    }
#pragma unroll
    for (int r = 0; r < 4; ++r) {
        int row = r0 + w * 16 + quad * 4 + r;
        if (row < N_NODES) {
            float mu = s1[r] * (1.f / 128.f);
            float var = s2[r] * (1.f / 128.f) - mu * mu;
            float rs = rsqrtf(var + 1e-5f);
#pragma unroll
            for (int nt = 0; nt < 8; ++nt) {
                int n = nt * 16 + l15;
                a[row * 128 + n] = (acc[nt][r] - mu) * rs * gamma1[n] + beta1[n];
            }
        }
    }
}

// ------- FFN + residual + LN2: DMA weight pipeline + register A-tile --------
// (unchanged from round 11: 67.5 us, VGPR 72, no spill, 3 blocks/CU)
__global__ __launch_bounds__(256) void k_ffn_ln(const float* __restrict__ h1,
                                                const u16* __restrict__ W3s,
                                                const float* __restrict__ b3,
                                                const u16* __restrict__ W4s,
                                                const float* __restrict__ b4,
                                                const float* __restrict__ gamma2,
                                                const float* __restrict__ beta2,
                                                float* __restrict__ out) {
    __shared__ __align__(16) u16 sY[64 * LDY];   //  9.2 KB (wave-private rows)
    __shared__ __align__(16) u16 sW3[8192];      // 16 KB linear W3 chunk
    __shared__ __align__(16) u16 sW4[8192];      // 16 KB linear W4 chunk
    int tid = threadIdx.x;
    int w = tid >> 6, lane = tid & 63;
    int l15 = tid & 15, quad = (tid & 63) >> 4;
    int r0 = blockIdx.x * 64;
    int dmaoff = w * 4096 + lane * 16;           // bytes; +j*1024 per call

    // 1) A-fragment loads FIRST (oldest in vmcnt order)
    int arow_g = r0 + w * 16 + l15; if (arow_g > N_NODES - 1) arow_g = N_NODES - 1;
    const float* ap = h1 + arow_g * 128 + quad * 8;
    float4 av0[4], av1[4];
#pragma unroll
    for (int kt = 0; kt < 4; ++kt) {
        av0[kt] = *(const float4*)(ap + kt * 32);
        av1[kt] = *(const float4*)(ap + kt * 32 + 4);
    }
    __builtin_amdgcn_sched_barrier(0);
    // 2) fire DMA for W3[0] and W4[0]
#pragma unroll
    for (int j = 0; j < 4; ++j)
        dma16((const u16*)((const char*)W3s + dmaoff + j * 1024),
              (u16*)((char*)sW3 + w * 4096 + j * 1024));
#pragma unroll
    for (int j = 0; j < 4; ++j)
        dma16((const u16*)((const char*)W4s + dmaoff + j * 1024),
              (u16*)((char*)sW4 + w * 4096 + j * 1024));
    __builtin_amdgcn_sched_barrier(0);
    // 3) convert to bf16 fragments (VALU covers DMA flight)
    bf16x8 af[4];
#pragma unroll
    for (int kt = 0; kt < 4; ++kt) {
        bf16x8 t;
        t[0] = (short)f2bf(av0[kt].x); t[1] = (short)f2bf(av0[kt].y);
        t[2] = (short)f2bf(av0[kt].z); t[3] = (short)f2bf(av0[kt].w);
        t[4] = (short)f2bf(av1[kt].x); t[5] = (short)f2bf(av1[kt].y);
        t[6] = (short)f2bf(av1[kt].z); t[7] = (short)f2bf(av1[kt].w);
        af[kt] = t;
    }
    asm volatile("s_waitcnt vmcnt(4)" ::: "memory");  // af+W3[0] retired; W4[0] flying
    __builtin_amdgcn_s_barrier();
    __builtin_amdgcn_sched_barrier(0);

    int arow = w * 16 + l15;
    f32x4 zero = {0.f, 0.f, 0.f, 0.f};
    f32x4 acc[8];
#pragma unroll
    for (int nt = 0; nt < 8; ++nt) acc[nt] = zero;

    for (int hc = 0; hc < 8; ++hc) {
        // gemmA: Y[16x64/wave] = af @ W3chunk (swizzled read)
        f32x4 y[4];
#pragma unroll
        for (int nt = 0; nt < 4; ++nt) y[nt] = zero;
#pragma unroll
        for (int kt = 0; kt < 4; ++kt) {
#pragma unroll
            for (int nt = 0; nt < 4; ++nt) {
                int r = nt * 16 + l15;
                bf16x8 bv = *(bf16x8*)&sW3[r * 128 + ((((kt << 2) + quad) ^ l15) << 3)];
                y[nt] = mfma16(af[kt], bv, y[nt]);
            }
        }
        // bias + relu -> sY (wave-private rows)
#pragma unroll
        for (int r = 0; r < 4; ++r) {
            int yrow = w * 16 + quad * 4 + r;
#pragma unroll
            for (int nt = 0; nt < 4; ++nt) {
                int n = nt * 16 + l15;
                float vv = y[nt][r] + b3[hc * 64 + n];
                sY[yrow * LDY + n] = f2bf(vv > 0.f ? vv : 0.f);
            }
        }
        __builtin_amdgcn_s_barrier();            // all done reading sW3[hc]
        __builtin_amdgcn_sched_barrier(0);
        {   // DMA W3[next] (dummy wrap at hc==7 keeps vmcnt counting uniform)
            const char* g3 = (const char*)W3s + ((hc + 1) & 7) * 16384;
#pragma unroll
            for (int j = 0; j < 4; ++j)
                dma16((const u16*)(g3 + dmaoff + j * 1024),
                      (u16*)((char*)sW3 + w * 4096 + j * 1024));
        }
        asm volatile("s_waitcnt vmcnt(4)" ::: "memory");  // own W4[hc] arrived
        __builtin_amdgcn_s_barrier();            // everyone's W4[hc] visible
        __builtin_amdgcn_sched_barrier(0);
        // gemmB: acc += Y @ W4chunk (K=64, swizzled read)
#pragma unroll
        for (int kt = 0; kt < 2; ++kt) {
            bf16x8 ay = *(bf16x8*)&sY[arow * LDY + kt * 32 + quad * 8];
#pragma unroll
            for (int nt = 0; nt < 8; ++nt) {
                int rr = nt * 16 + l15;
                bf16x8 bv = *(bf16x8*)&sW4[rr * 64 + ((((kt << 2) + quad) ^ (l15 & 7)) << 3)];
                acc[nt] = mfma16(ay, bv, acc[nt]);
            }
        }
        if (hc == 7) break;
        __builtin_amdgcn_s_barrier();            // all done reading sW4[hc]
        __builtin_amdgcn_sched_barrier(0);
        {   // DMA W4[hc+1]
            const char* g4 = (const char*)W4s + (hc + 1) * 16384;
#pragma unroll
            for (int j = 0; j < 4; ++j)
                dma16((const u16*)(g4 + dmaoff + j * 1024),
                      (u16*)((char*)sW4 + w * 4096 + j * 1024));
        }
        asm volatile("s_waitcnt vmcnt(4)" ::: "memory");  // own W3[hc+1] arrived
        __builtin_amdgcn_s_barrier();            // everyone's W3[hc+1] visible
        __builtin_amdgcn_sched_barrier(0);
    }
    // epilogue: residual + LN2 (round-4 proven)
    float s1[4] = {0, 0, 0, 0}, s2[4] = {0, 0, 0, 0};
#pragma unroll
    for (int r = 0; r < 4; ++r) {
        int row = r0 + w * 16 + quad * 4 + r;
        int rc = row > N_NODES - 1 ? N_NODES - 1 : row;
#pragma unroll
        for (int nt = 0; nt < 8; ++nt) {
            int n = nt * 16 + l15;
            float t = acc[nt][r] + b4[n] + h1[rc * 128 + n];
            acc[nt][r] = t;
            s1[r] += t; s2[r] += t * t;
        }
    }
#pragma unroll
    for (int off = 1; off < 16; off <<= 1) {
#pragma unroll
        for (int r = 0; r < 4; ++r) {
            s1[r] += __shfl_xor(s1[r], off, 64);
            s2[r] += __shfl_xor(s2[r], off, 64);
        }
    }
#pragma unroll
    for (int r = 0; r < 4; ++r) {
        int row = r0 + w * 16 + quad * 4 + r;
        if (row < N_NODES) {
            float mu = s1[r] * (1.f / 128.f);
            float var = s2[r] * (1.f / 128.f) - mu * mu;
            float rs = rsqrtf(var + 1e-5f);
#pragma unroll
            for (int nt = 0; nt < 8; ++nt) {
                int n = nt * 16 + l15;
                out[row * 128 + n] = (acc[nt][r] - mu) * rs * gamma2[n] + beta2[n];
            }
        }
    }
}

extern "C" void kernel_launch(void* const* d_in, const int* in_sizes, int n_in,
                              void* d_out, int out_size, void* d_ws, size_t ws_size,
                              hipStream_t stream) {
    const float* h      = (const float*)d_in[0];
    const int*   src    = (const int*)d_in[1];
    const int*   dst    = (const int*)d_in[2];
    const float* W1     = (const float*)d_in[3];
    const float* b1     = (const float*)d_in[4];
    const float* W2     = (const float*)d_in[5];
    const float* b2     = (const float*)d_in[6];
    const float* W3     = (const float*)d_in[7];
    const float* b3     = (const float*)d_in[8];
    const float* W4     = (const float*)d_in[9];
    const float* b4     = (const float*)d_in[10];
    const float* gamma1 = (const float*)d_in[11];
    const float* beta1  = (const float*)d_in[12];
    const float* gamma2 = (const float*)d_in[13];
    const float* beta2  = (const float*)d_in[14];
    float* out = (float*)d_out;

    // ws layout (bytes), with dead-region aliasing:
    // ptr_node int[100001]     @ 0
    // ptr_he   int[20001]      @ 400512
    // adj_he   int[1.6M]       @ 481280    } hh2b bf16[20000*128] aliases after gather1
    // adj_node int[1.6M]       @ 6881280
    // cn       f32[100000]     @ 13281280
    // ch       f32[20000]      @ 13681280
    // h_bf     bf16[100000*128]@ 24000000..49600000  } acc2 span head
    // bin_he   u32[79*24576]   @ 49600000..57366016  } dead after k_fill2
    // bin_nd   u32[391*5120]   @ 57366016..65373696  } dead after k_fill2
    // acc1     f32[20000*128]  @ 49600000..59840000  (aliases bins; written at gather1)
    // bkt_he[79]/bkt_nd[391]   @ 72640000  (zeroed reservation counters)
    // bs int[30]               @ 72644864
    // acc2/h1  f32[100000*128] @ 24000000..75200000 (written at gather2)
    // W1t/W2t/W3t/W4t          @ 75200000..75527680
    char* ws = (char*)d_ws;
    int*   ptr_node = (int*)(ws + 0);
    int*   ptr_he   = (int*)(ws + 400512);
    int*   adj_he   = (int*)(ws + 481280);
    int*   adj_node = (int*)(ws + 6881280);
    float* cn       = (float*)(ws + 13281280);
    float* ch       = (float*)(ws + 13681280);
    u16*   h_bf     = (u16*)(ws + 24000000);
    u32*   bin_he   = (u32*)(ws + 49600000);
    u32*   bin_nd   = (u32*)(ws + 57366016);
    float* acc1     = (float*)(ws + 49600000);   // alias bins (dead after k_fill2)
    int*   bkt_he   = (int*)(ws + 72640000);
    int*   bkt_nd   = (int*)(ws + 72640512);
    int*   bs       = (int*)(ws + 72644864);
    float* acc2     = (float*)(ws + 24000000);
    u16*   hh2b     = (u16*)(ws + 481280);     // alias adj_he (dead after gather1)
    u16*   W1t      = (u16*)(ws + 75200000);
    u16*   W2t      = (u16*)(ws + 75232768);
    u16*   W3t      = (u16*)(ws + 75265536);
    u16*   W4t      = (u16*)(ws + 75396608);

    hipMemsetAsync(ws + 72640000, 0, 2560, stream);   // zero bucket reservation counters

    k_prep<<<12800, 256, 0, stream>>>(W1, W2, W3, W4, W1t, W2t, W3t, W4t, h, h_bf);
    k_bin_fill<<<800, 256, 0, stream>>>(src, dst, bkt_he, bkt_nd, bin_he, bin_nd);
    k_deg<<<NB_HE + NB_ND, 256, 0, stream>>>(bin_he, bin_nd, bkt_he, bkt_nd, ptr_node, ptr_he);
    k_scanA<<<30, 256, 0, stream>>>(ptr_node, ptr_he, bs);
    k_scanB<<<1, 64, 0, stream>>>(bs, ptr_node, ptr_he);
    k_scanC<<<30, 256, 0, stream>>>(ptr_node, ptr_he, cn, ch, bs);
    k_fill2<<<NB_HE + NB_ND, 256, 0, stream>>>(bin_he, bin_nd, bkt_he, bkt_nd,
                                               ptr_he, ptr_node, adj_he, adj_node);
    k_gather1<<<5000, 256, 0, stream>>>(h_bf, adj_he, ptr_he, cn, acc1);
    k_gemm1<<<313, 256, 0, stream>>>(acc1, ch, W1t, b1, hh2b);
    k_gather2<<<25000, 256, 0, stream>>>(hh2b, adj_node, ptr_node, acc2);
    k_gemm2_ln<<<1563, 256, 0, stream>>>(acc2, cn, W2t, b2, h, gamma1, beta1);
    k_ffn_ln<<<1563, 256, 0, stream>>>(acc2, W3t, b3, W4t, b4, gamma2, beta2, out);
}